// Round 12
// baseline (608.622 us; speedup 1.0000x reference)
//
#include <hip/hip_runtime.h>
#include <hip/hip_bf16.h>

#define N_ 2
#define C_ 64
#define D_ 8
#define H_ 56
#define W_ 56
#define HW_ (H_*W_)        // 3136
#define P_ (D_*HW_)        // 25088
#define G_ 8
#define CPG_ 8
#define K_ 27
#define CO_OFF_ 648        // G * 3 * K
#define MP_ 768            // conv_off M padded (rows 648+ zero)
#define KK_ 1728           // GEMM K dim (= 27*64, k-major: ktap*64 + ci)
#define KB_ (KK_*2)        // bytes per bf16 row

typedef __attribute__((ext_vector_type(8))) short shortx8;
typedef __attribute__((ext_vector_type(4))) float floatx4;
#define AS1 __attribute__((address_space(1)))
#define AS3 __attribute__((address_space(3)))

__device__ inline float b2f(unsigned short u) {
    union { unsigned u; float f; } x; x.u = ((unsigned)u) << 16; return x.f;
}
__device__ inline unsigned short f2b(float f) {
    union { float f; unsigned u; } x; x.f = f;
    unsigned r = (x.u + 0x7fffu + ((x.u >> 16) & 1u)) >> 16;   // RNE
    return (unsigned short)r;
}
__device__ inline float lof(unsigned u) { union { unsigned u; float f; } x; x.u = u << 16; return x.f; }
__device__ inline float hif(unsigned u) { union { unsigned u; float f; } x; x.u = u & 0xffff0000u; return x.f; }

// ---------------------------------------------------------------------------
// x [N][64][P] fp32 -> xt [N][P][64] bf16  (64p x 64c LDS tile transpose)
// ---------------------------------------------------------------------------
__global__ __launch_bounds__(256) void transpose_xt_kernel(
    const float* __restrict__ x, unsigned short* __restrict__ xt)
{
    __shared__ unsigned short tile[64][65];
    int b  = blockIdx.x;
    int n  = b / (P_/64);
    int p0 = (b % (P_/64))*64;
    int tid = threadIdx.x;
    int j  = tid & 63;
    int c0 = (tid >> 6)*16;
    for (int r = 0; r < 16; ++r)
        tile[c0 + r][j] = f2b(x[((size_t)n*C_ + c0 + r)*P_ + p0 + j]);
    __syncthreads();
    unsigned* dst = (unsigned*)(xt + ((size_t)n*P_ + p0)*C_);
    #pragma unroll
    for (int it = 0; it < 8; ++it) {
        int wi  = it*256 + tid;
        int row = wi >> 5;
        int c   = (wi & 31)*2;
        unsigned lo = tile[c][row], hi = tile[c+1][row];
        dst[(size_t)row*32 + (wi & 31)] = lo | (hi << 16);
    }
}

// w_off [648][64][27] fp32 -> A1k [768][kk*64+ci] bf16 (k-major, zero-pad rows)
__global__ __launch_bounds__(256) void permA1k_kernel(
    const float* __restrict__ w, unsigned short* __restrict__ A)
{
    int i = blockIdx.x*256 + threadIdx.x;
    if (i >= MP_*KK_) return;
    int m = i / KK_, r = i % KK_;
    int kk = r / 64, ci = r % 64;
    A[i] = (m < CO_OFF_) ? f2b(w[((size_t)m*C_ + ci)*K_ + kk]) : (unsigned short)0;
}

// w [O=64][I=64][27] fp32 -> At[o][k*64+i] bf16 (k-major)
__global__ __launch_bounds__(256) void perm_w_kernel(
    const float* __restrict__ w, unsigned short* __restrict__ At)
{
    int tid = blockIdx.x*256 + threadIdx.x;
    if (tid >= C_*KK_) return;
    int o  = tid / KK_;
    int r  = tid % KK_;
    int k  = r / 64, i = r % 64;
    At[tid] = f2b(w[((size_t)o*C_ + i)*K_ + k]);
}

// ---------------------------------------------------------------------------
// conv_off fused main: m-tiles 0..4 only (rows 0..639, all valid). Pipelined.
// ---------------------------------------------------------------------------
__global__ __launch_bounds__(256) void conv_off_fused(
    const unsigned short* __restrict__ A,    // A1k [768][1728]
    const unsigned short* __restrict__ xt,   // [N][P][64] bf16
    const float* __restrict__ bias,          // [648]
    unsigned short* __restrict__ off)        // [N][648][P] bf16
{
    __shared__ __align__(16) short As[2][16*512];
    __shared__ __align__(16) short Bs[16*512];
    int tid = threadIdx.x;
    int w = tid >> 6, lane = tid & 63;
    int n   = blockIdx.x / 980;
    int bid = blockIdx.x % 980;
    int mt, nt;
    if (bid < 960) { int c = bid/40, r = bid%40; mt = r >> 3; nt = c*8 + (r&7); }
    else           { int r = bid - 960;          mt = r >> 2; nt = 192 + (r&3); }
    int m0 = mt*128, p0 = nt*128;
    int lm = lane & 15, lq = lane >> 4;

    const unsigned short* xtn = xt + (size_t)n*P_*C_;
    unsigned short* out = off + (size_t)n*CO_OFF_*P_;

    const char* Ab0 = (const char*)A + (size_t)(m0 + w*32 + lm)*KB_ + lq*16;
    const char* Ab1 = Ab0 + (size_t)16*KB_;

    int oct = lane & 7;
    int prj[4], dj[4], hj[4], wj[4];
    #pragma unroll
    for (int j = 0; j < 4; ++j) {
        int prow = j*32 + w*8 + (lane >> 3);
        prj[j] = prow;
        int p = p0 + prow;
        dj[j] = p / HW_;
        int hw2 = p % HW_;
        hj[j] = hw2 / W_;
        wj[j] = hw2 % W_;
    }

    auto stageA = [&](int kt, int buf) {
        __builtin_amdgcn_global_load_lds((const AS1 unsigned*)(Ab0 + kt*128),      (AS3 unsigned*)(&As[buf][(w*2)*512]),     16, 0, 0);
        __builtin_amdgcn_global_load_lds((const AS1 unsigned*)(Ab1 + kt*128),      (AS3 unsigned*)(&As[buf][(w*2+1)*512]),   16, 0, 0);
        __builtin_amdgcn_global_load_lds((const AS1 unsigned*)(Ab0 + kt*128 + 64), (AS3 unsigned*)(&As[buf][(8+w*2)*512]),   16, 0, 0);
        __builtin_amdgcn_global_load_lds((const AS1 unsigned*)(Ab1 + kt*128 + 64), (AS3 unsigned*)(&As[buf][(8+w*2+1)*512]), 16, 0, 0);
    };
    auto loadB = [&](int kt, uint4* B) {
        int kd = kt/9 - 1, kh = (kt/3)%3 - 1, kw = kt%3 - 1;
        int delta = kd*HW_ + kh*W_ + kw;
        #pragma unroll
        for (int j = 0; j < 4; ++j) {
            bool v = ((unsigned)(dj[j]+kd) < (unsigned)D_) &&
                     ((unsigned)(hj[j]+kh) < (unsigned)H_) &&
                     ((unsigned)(wj[j]+kw) < (unsigned)W_);
            uint4 val = {0u,0u,0u,0u};
            if (v) val = *(const uint4*)(xtn + (size_t)(p0 + prj[j] + delta)*C_ + oct*8);
            B[j] = val;
        }
    };

    int mh = w >> 1, nh = w & 1;
    floatx4 acc[4][4];
    #pragma unroll
    for (int i = 0; i < 4; ++i)
        #pragma unroll
        for (int j = 0; j < 4; ++j)
            acc[i][j] = (floatx4){0.f, 0.f, 0.f, 0.f};

    uint4 Bcur[4], Bnext[4];
    #pragma unroll
    for (int j = 0; j < 4; ++j) Bnext[j] = (uint4){0u,0u,0u,0u};
    stageA(0, 0);
    loadB(0, Bcur);

    for (int kt = 0; kt < 27; ++kt) {
        int buf = kt & 1;
        __syncthreads();
        #pragma unroll
        for (int j = 0; j < 4; ++j) {
            int chunk = (oct>>2)*8 + (prj[j]>>4);
            *(uint4*)&Bs[chunk*512 + ((oct&3)*16 + ((prj[j]&15) ^ oct))*8] = Bcur[j];
        }
        __syncthreads();
        if (kt < 26) { stageA(kt+1, buf^1); loadB(kt+1, Bnext); }
        #pragma unroll
        for (int ks = 0; ks < 2; ++ks) {
            int swzB = (lq*16 + (lm ^ (ks*4 + lq)))*8;
            shortx8 a[4], b[4];
            #pragma unroll
            for (int i = 0; i < 4; ++i) a[i] = *(const shortx8*)&As[buf][(ks*8 + 4*mh + i)*512 + lane*8];
            #pragma unroll
            for (int j = 0; j < 4; ++j) b[j] = *(const shortx8*)&Bs[(ks*8 + 4*nh + j)*512 + swzB];
            #pragma unroll
            for (int i = 0; i < 4; ++i)
                #pragma unroll
                for (int j = 0; j < 4; ++j)
                    acc[i][j] = __builtin_amdgcn_mfma_f32_16x16x32_bf16(a[i], b[j], acc[i][j], 0, 0, 0);
        }
        #pragma unroll
        for (int j = 0; j < 4; ++j) Bcur[j] = Bnext[j];
    }

    #pragma unroll
    for (int i = 0; i < 4; ++i) {
        int cob = m0 + (4*mh+i)*16 + lq*4;
        #pragma unroll
        for (int r = 0; r < 4; ++r) {
            int co = cob + r;    // < 640 always (mt <= 4)
            float bv = bias[co];
            #pragma unroll
            for (int j = 0; j < 4; ++j) {
                int col = p0 + (4*nh+j)*16 + lm;
                out[(size_t)co*P_ + col] = f2b(acc[i][j][r] + bv);
            }
        }
    }
}

// ---------------------------------------------------------------------------
// conv_off tail: rows 640..655 (648..655 zero-padded). 16x128 tile.
// ---------------------------------------------------------------------------
__global__ __launch_bounds__(256) void conv_off_tail(
    const unsigned short* __restrict__ A,    // A1k [768][1728]
    const unsigned short* __restrict__ xt,   // [N][P][64] bf16
    const float* __restrict__ bias,          // [648]
    unsigned short* __restrict__ off)        // [N][648][P] bf16
{
    __shared__ __align__(16) short As[54*512];
    __shared__ __align__(16) short Bs[16*512];
    int tid = threadIdx.x;
    int w = tid >> 6, lane = tid & 63;
    int n  = blockIdx.x / 196;
    int p0 = (blockIdx.x % 196)*128;
    int lm = lane & 15, lq = lane >> 4;

    const unsigned short* xtn = xt + (size_t)n*P_*C_;
    unsigned short* out = off + (size_t)n*CO_OFF_*P_;

    const char* Abase = (const char*)A + (size_t)(640 + lm)*KB_ + lq*16;
    for (int ch = w; ch < 54; ch += 4)
        __builtin_amdgcn_global_load_lds((const AS1 unsigned*)(Abase + ch*64),
                                         (AS3 unsigned*)(As + ch*512), 16, 0, 0);

    int oct = lane & 7;
    int prj[4], dj[4], hj[4], wj[4];
    #pragma unroll
    for (int j = 0; j < 4; ++j) {
        int prow = j*32 + w*8 + (lane >> 3);
        prj[j] = prow;
        int p = p0 + prow;
        dj[j] = p / HW_;
        int hw2 = p % HW_;
        hj[j] = hw2 / W_;
        wj[j] = hw2 % W_;
    }
    auto loadB = [&](int kt, uint4* B) {
        int kd = kt/9 - 1, kh = (kt/3)%3 - 1, kw = kt%3 - 1;
        int delta = kd*HW_ + kh*W_ + kw;
        #pragma unroll
        for (int j = 0; j < 4; ++j) {
            bool v = ((unsigned)(dj[j]+kd) < (unsigned)D_) &&
                     ((unsigned)(hj[j]+kh) < (unsigned)H_) &&
                     ((unsigned)(wj[j]+kw) < (unsigned)W_);
            uint4 val = {0u,0u,0u,0u};
            if (v) val = *(const uint4*)(xtn + (size_t)(p0 + prj[j] + delta)*C_ + oct*8);
            B[j] = val;
        }
    };

    floatx4 acc[2];
    acc[0] = (floatx4){0.f,0.f,0.f,0.f};
    acc[1] = (floatx4){0.f,0.f,0.f,0.f};

    uint4 Bcur[4], Bnext[4];
    #pragma unroll
    for (int j = 0; j < 4; ++j) Bnext[j] = (uint4){0u,0u,0u,0u};
    loadB(0, Bcur);

    for (int kt = 0; kt < 27; ++kt) {
        __syncthreads();
        #pragma unroll
        for (int j = 0; j < 4; ++j) {
            int chunk = (oct>>2)*8 + (prj[j]>>4);
            *(uint4*)&Bs[chunk*512 + ((oct&3)*16 + ((prj[j]&15) ^ oct))*8] = Bcur[j];
        }
        __syncthreads();
        if (kt < 26) loadB(kt+1, Bnext);
        #pragma unroll
        for (int ks = 0; ks < 2; ++ks) {
            int swzB = (lq*16 + (lm ^ (ks*4 + lq)))*8;
            shortx8 a = *(const shortx8*)&As[(kt*2 + ks)*512 + lane*8];
            #pragma unroll
            for (int j = 0; j < 2; ++j) {
                shortx8 b = *(const shortx8*)&Bs[(ks*8 + w*2 + j)*512 + swzB];
                acc[j] = __builtin_amdgcn_mfma_f32_16x16x32_bf16(a, b, acc[j], 0, 0, 0);
            }
        }
        #pragma unroll
        for (int j = 0; j < 4; ++j) Bcur[j] = Bnext[j];
    }

    #pragma unroll
    for (int j = 0; j < 2; ++j) {
        #pragma unroll
        for (int r = 0; r < 4; ++r) {
            int co = 640 + lq*4 + r;
            if (co < CO_OFF_) {
                int col = p0 + w*32 + j*16 + lm;
                out[(size_t)co*P_ + col] = f2b(acc[j][r] + bias[co]);
            }
        }
    }
}

// ---------------------------------------------------------------------------
// deform fused v3: register-B. Wave owns 16 p (lm) x all 64 o; per kt, lane's
// two gather tasks (g = ks*4+lq) ARE the two B fragments. No LDS for B, one
// barrier per kt (A dbuf only). Direct-store epilogue.
// ---------------------------------------------------------------------------
__global__ __launch_bounds__(256) void deform_fused(
    const unsigned short* __restrict__ xt,   // [N][P][64] bf16
    const unsigned short* __restrict__ off,  // [N][648][P] bf16
    const unsigned short* __restrict__ A,    // A1t [64][1728]
    unsigned short* __restrict__ y1t)        // [N][P][64] bf16
{
    __shared__ __align__(16) short As[2][4096];   // per kt: 8 chunks of 512
    int tid = threadIdx.x;
    int w = tid >> 6, lane = tid & 63;
    int n  = blockIdx.x / (P_/64);
    int p0 = (blockIdx.x % (P_/64))*64;
    int lm = lane & 15, lq = lane >> 4;

    const unsigned short* offn = off + (size_t)n*CO_OFF_*P_;
    const uint4* xg0 = (const uint4*)(xt + (size_t)n*P_*C_);
    const char* Ab = (const char*)A + (size_t)(w*16 + lm)*KB_ + lq*16;

    int p = p0 + w*16 + lm;
    int dd = p / HW_, hw2 = p % HW_;
    int hh = hw2 / W_, ww = hw2 % W_;

    auto stageA = [&](int kt, int buf) {
        __builtin_amdgcn_global_load_lds((const AS1 unsigned*)(Ab + kt*128),      (AS3 unsigned*)(&As[buf][w*512]),     16, 0, 0);
        __builtin_amdgcn_global_load_lds((const AS1 unsigned*)(Ab + kt*128 + 64), (AS3 unsigned*)(&As[buf][(4+w)*512]), 16, 0, 0);
    };
    auto loadOff = [&](int kt, float* o) {   // o[6] = 2 tasks x 3 comps
        #pragma unroll
        for (int ks = 0; ks < 2; ++ks) {
            int g = ks*4 + lq;
            size_t ob = ((size_t)(g*K_ + kt)*3)*P_ + p;
            o[ks*3+0] = b2f(offn[ob]);
            o[ks*3+1] = b2f(offn[ob + P_]);
            o[ks*3+2] = b2f(offn[ob + 2*(size_t)P_]);
        }
    };
    auto issueCorners = [&](int kt, float* o, uint4 V[2][8], float Wt[2][8]) {
        int kd = kt/9 - 1, kh = (kt/3)%3 - 1, kw = kt%3 - 1;
        #pragma unroll
        for (int ks = 0; ks < 2; ++ks) {
            int g = ks*4 + lq;
            float pd = (float)(dd + kd) + o[ks*3+0];
            float ph = (float)(hh + kh) + o[ks*3+1];
            float pw = (float)(ww + kw) + o[ks*3+2];
            float fd0 = floorf(pd), fh0 = floorf(ph), fw0 = floorf(pw);
            int d0 = (int)fd0, h0 = (int)fh0, w0i = (int)fw0;
            float fd = pd - fd0, fh = ph - fh0, fw = pw - fw0;
            int idx = 0;
            #pragma unroll
            for (int cd = 0; cd < 2; ++cd) {
                int id = d0 + cd;
                float wdt = cd ? fd : 1.f - fd;
                bool vdd = (unsigned)id < (unsigned)D_;
                int idc = min(max(id, 0), D_-1);
                #pragma unroll
                for (int ch = 0; ch < 2; ++ch) {
                    int ih = h0 + ch;
                    float wht = ch ? fh : 1.f - fh;
                    bool vhh = (unsigned)ih < (unsigned)H_;
                    int ihc = min(max(ih, 0), H_-1);
                    #pragma unroll
                    for (int cw = 0; cw < 2; ++cw) {
                        int iw = w0i + cw;
                        float wwt = cw ? fw : 1.f - fw;
                        bool vww = (unsigned)iw < (unsigned)W_;
                        int iwc = min(max(iw, 0), W_-1);
                        int lin = (idc*H_ + ihc)*W_ + iwc;
                        V[ks][idx]  = xg0[(size_t)lin*(C_/8) + g];
                        Wt[ks][idx] = (vdd && vhh && vww) ? wdt*wht*wwt : 0.f;
                        ++idx;
                    }
                }
            }
        }
    };
    auto reduceT = [&](uint4* V, float* Wt) -> shortx8 {
        float res[8];
        #pragma unroll
        for (int c = 0; c < 8; ++c) res[c] = 0.f;
        #pragma unroll
        for (int c = 0; c < 8; ++c) {
            uint4 v4 = V[c];
            float wgt = Wt[c];
            res[0] = fmaf(wgt, lof(v4.x), res[0]);
            res[1] = fmaf(wgt, hif(v4.x), res[1]);
            res[2] = fmaf(wgt, lof(v4.y), res[2]);
            res[3] = fmaf(wgt, hif(v4.y), res[3]);
            res[4] = fmaf(wgt, lof(v4.z), res[4]);
            res[5] = fmaf(wgt, hif(v4.z), res[5]);
            res[6] = fmaf(wgt, lof(v4.w), res[6]);
            res[7] = fmaf(wgt, hif(v4.w), res[7]);
        }
        uint4 o4;
        o4.x = (unsigned)f2b(res[0]) | ((unsigned)f2b(res[1]) << 16);
        o4.y = (unsigned)f2b(res[2]) | ((unsigned)f2b(res[3]) << 16);
        o4.z = (unsigned)f2b(res[4]) | ((unsigned)f2b(res[5]) << 16);
        o4.w = (unsigned)f2b(res[6]) | ((unsigned)f2b(res[7]) << 16);
        return *(shortx8*)&o4;
    };

    floatx4 acc[4];
    #pragma unroll
    for (int i = 0; i < 4; ++i) acc[i] = (floatx4){0.f,0.f,0.f,0.f};

    float offA[6], offB[6], offT[6];
    uint4 V[2][8]; float Wt[2][8];

    stageA(0, 0);
    loadOff(0, offA);
    loadOff(1, offB);
    issueCorners(0, offA, V, Wt);

    for (int kt = 0; kt < 27; ++kt) {
        int buf = kt & 1;
        __syncthreads();                      // A(kt) staged; safe to overwrite buf^1
        if (kt < 26) stageA(kt+1, buf^1);
        if (kt < 25) loadOff(kt+2, offT);
        shortx8 b0 = reduceT(V[0], Wt[0]);    // waits on corners issued last iter
        shortx8 b1 = reduceT(V[1], Wt[1]);
        if (kt < 26) issueCorners(kt+1, offB, V, Wt);
        #pragma unroll
        for (int i = 0; i < 4; ++i) {
            shortx8 a = *(const shortx8*)&As[buf][(0*4 + i)*512 + lane*8];
            acc[i] = __builtin_amdgcn_mfma_f32_16x16x32_bf16(a, b0, acc[i], 0, 0, 0);
        }
        #pragma unroll
        for (int i = 0; i < 4; ++i) {
            shortx8 a = *(const shortx8*)&As[buf][(1*4 + i)*512 + lane*8];
            acc[i] = __builtin_amdgcn_mfma_f32_16x16x32_bf16(a, b1, acc[i], 0, 0, 0);
        }
        if (kt < 26) {
            #pragma unroll
            for (int q = 0; q < 6; ++q) offB[q] = offT[q];
        }
    }

    // epilogue: lane owns column p; acc[i][r] -> o = i*16 + lq*4 + r
    unsigned short* dst = y1t + ((size_t)n*P_ + p)*C_;
    #pragma unroll
    for (int i = 0; i < 4; ++i) {
        unsigned lo = (unsigned)f2b(acc[i][0]) | ((unsigned)f2b(acc[i][1]) << 16);
        unsigned hi = (unsigned)f2b(acc[i][2]) | ((unsigned)f2b(acc[i][3]) << 16);
        uint2 v; v.x = lo; v.y = hi;
        *(uint2*)(dst + i*16 + lq*4) = v;
    }
}

// ---------------------------------------------------------------------------
// conv2 fused v3: register-B. Lane's B-frag (ks) = one masked 16B load of
// y1t[p+delta] channels (ks*4+lq)*8.. + BN+ReLU+pack. No LDS for B.
// ---------------------------------------------------------------------------
__global__ __launch_bounds__(256) void conv2_fused(
    const unsigned short* __restrict__ y1t,  // [N][P][64] bf16
    const float* __restrict__ st1,           // [64] scale, [64] shift
    const unsigned short* __restrict__ A,    // A2t [64][1728]
    const float* __restrict__ bias,          // [64]
    unsigned short* __restrict__ y2)         // [N][64][P] bf16
{
    __shared__ __align__(16) short As[2][4096];
    __shared__ float sc[64], sf[64];
    int tid = threadIdx.x;
    if (tid < 64) sc[tid] = st1[tid];
    else if (tid < 128) sf[tid-64] = st1[tid];
    int w = tid >> 6, lane = tid & 63;
    int n  = blockIdx.x / (P_/64);
    int p0 = (blockIdx.x % (P_/64))*64;
    int lm = lane & 15, lq = lane >> 4;

    const unsigned short* y1n = y1t + (size_t)n*P_*C_;
    unsigned short* y2n = y2 + (size_t)n*C_*P_;
    const char* Ab = (const char*)A + (size_t)(w*16 + lm)*KB_ + lq*16;

    int p = p0 + w*16 + lm;
    int dd = p / HW_, hw2 = p % HW_;
    int hh = hw2 / W_, ww = hw2 % W_;

    auto stageA = [&](int kt, int buf) {
        __builtin_amdgcn_global_load_lds((const AS1 unsigned*)(Ab + kt*128),      (AS3 unsigned*)(&As[buf][w*512]),     16, 0, 0);
        __builtin_amdgcn_global_load_lds((const AS1 unsigned*)(Ab + kt*128 + 64), (AS3 unsigned*)(&As[buf][(4+w)*512]), 16, 0, 0);
    };
    auto issueV = [&](int kt, uint4* V, int& M) {
        int kd = kt/9 - 1, kh = (kt/3)%3 - 1, kw = kt%3 - 1;
        int delta = kd*HW_ + kh*W_ + kw;
        bool v = ((unsigned)(dd+kd) < (unsigned)D_) &&
                 ((unsigned)(hh+kh) < (unsigned)H_) &&
                 ((unsigned)(ww+kw) < (unsigned)W_);
        M = v ? 1 : 0;
        #pragma unroll
        for (int ks = 0; ks < 2; ++ks) {
            uint4 val = {0u,0u,0u,0u};
            if (v) val = *(const uint4*)(y1n + (size_t)(p + delta)*C_ + (ks*4 + lq)*8);
            V[ks] = val;
        }
    };
    auto reduceT = [&](uint4 V, int ks, int M) -> shortx8 {
        uint4 o4 = {0u,0u,0u,0u};
        if (M) {
            int cb = (ks*4 + lq)*8;
            float r0 = fmaxf(lof(V.x)*sc[cb+0] + sf[cb+0], 0.f);
            float r1 = fmaxf(hif(V.x)*sc[cb+1] + sf[cb+1], 0.f);
            float r2 = fmaxf(lof(V.y)*sc[cb+2] + sf[cb+2], 0.f);
            float r3 = fmaxf(hif(V.y)*sc[cb+3] + sf[cb+3], 0.f);
            float r4 = fmaxf(lof(V.z)*sc[cb+4] + sf[cb+4], 0.f);
            float r5 = fmaxf(hif(V.z)*sc[cb+5] + sf[cb+5], 0.f);
            float r6 = fmaxf(lof(V.w)*sc[cb+6] + sf[cb+6], 0.f);
            float r7 = fmaxf(hif(V.w)*sc[cb+7] + sf[cb+7], 0.f);
            o4.x = (unsigned)f2b(r0) | ((unsigned)f2b(r1) << 16);
            o4.y = (unsigned)f2b(r2) | ((unsigned)f2b(r3) << 16);
            o4.z = (unsigned)f2b(r4) | ((unsigned)f2b(r5) << 16);
            o4.w = (unsigned)f2b(r6) | ((unsigned)f2b(r7) << 16);
        }
        return *(shortx8*)&o4;
    };

    floatx4 acc[4];
    #pragma unroll
    for (int i = 0; i < 4; ++i) acc[i] = (floatx4){0.f,0.f,0.f,0.f};

    uint4 V[2];
    int M;
    stageA(0, 0);
    issueV(0, V, M);

    for (int kt = 0; kt < 27; ++kt) {
        int buf = kt & 1;
        __syncthreads();                     // also makes sc/sf visible (kt=0)
        if (kt < 26) stageA(kt+1, buf^1);
        shortx8 b0 = reduceT(V[0], 0, M);
        shortx8 b1 = reduceT(V[1], 1, M);
        if (kt < 26) issueV(kt+1, V, M);
        #pragma unroll
        for (int i = 0; i < 4; ++i) {
            shortx8 a = *(const shortx8*)&As[buf][(0*4 + i)*512 + lane*8];
            acc[i] = __builtin_amdgcn_mfma_f32_16x16x32_bf16(a, b0, acc[i], 0, 0, 0);
        }
        #pragma unroll
        for (int i = 0; i < 4; ++i) {
            shortx8 a = *(const shortx8*)&As[buf][(1*4 + i)*512 + lane*8];
            acc[i] = __builtin_amdgcn_mfma_f32_16x16x32_bf16(a, b1, acc[i], 0, 0, 0);
        }
    }

    #pragma unroll
    for (int i = 0; i < 4; ++i) {
        #pragma unroll
        for (int r = 0; r < 4; ++r) {
            int co = i*16 + lq*4 + r;
            y2n[(size_t)co*P_ + p] = f2b(acc[i][r] + bias[co]);
        }
    }
}

// ---------------------------------------------------------------------------
// BN1 stats from y1t [N*P][64]: partial sums per 512-row block, then finalize
// ---------------------------------------------------------------------------
__global__ __launch_bounds__(256) void stats_partial_kernel(
    const unsigned short* __restrict__ y1t, float* __restrict__ part)
{
    int b = blockIdx.x, tid = threadIdx.x;
    int c = tid & 63, sub = tid >> 6;
    float s = 0.f, q = 0.f;
    for (int rr = 0; rr < 128; ++rr) {
        int row = b*512 + sub*128 + rr;
        float v = b2f(y1t[(size_t)row*C_ + c]);
        s += v;
        q = fmaf(v, v, q);
    }
    __shared__ float ss[256], qq[256];
    ss[tid] = s; qq[tid] = q;
    __syncthreads();
    if (tid < 64) {
        float S = ss[tid] + ss[64+tid] + ss[128+tid] + ss[192+tid];
        float Q = qq[tid] + qq[64+tid] + qq[128+tid] + qq[192+tid];
        part[b*128 + tid]      = S;
        part[b*128 + 64 + tid] = Q;
    }
}

__global__ void stats_final_kernel(
    const float* __restrict__ part,
    const float* __restrict__ gamma, const float* __restrict__ beta,
    float* __restrict__ st1)
{
    int c = threadIdx.x;  // 64 threads
    float S = 0.f, Q = 0.f;
    for (int b = 0; b < 98; ++b) {
        S += part[b*128 + c];
        Q += part[b*128 + 64 + c];
    }
    const float inv = 1.f / (float)(N_*P_);
    float m = S * inv;
    float var = Q * inv - m*m;
    float scale = rsqrtf(var + 1e-5f) * gamma[c];
    st1[c]      = scale;
    st1[64 + c] = beta[c] - m*scale;
}

// ---------------------------------------------------------------------------
__global__ __launch_bounds__(256) void bn_stats_kernel(
    const unsigned short* __restrict__ src, float* __restrict__ stats)
{
    int c   = blockIdx.x;
    int tid = threadIdx.x;
    float s = 0.f, q = 0.f;
    for (int n = 0; n < N_; ++n) {
        const unsigned short* p = src + ((size_t)n*C_ + c)*P_;
        for (int i = tid; i < P_; i += 256) {
            float v = b2f(p[i]);
            s += v;
            q = fmaf(v, v, q);
        }
    }
    #pragma unroll
    for (int o = 32; o; o >>= 1) {
        s += __shfl_down(s, o);
        q += __shfl_down(q, o);
    }
    __shared__ float sh[2][4];
    int wave = tid >> 6;
    if ((tid & 63) == 0) { sh[0][wave] = s; sh[1][wave] = q; }
    __syncthreads();
    if (tid == 0) {
        float S = sh[0][0] + sh[0][1] + sh[0][2] + sh[0][3];
        float Q = sh[1][0] + sh[1][1] + sh[1][2] + sh[1][3];
        const float inv = 1.f / (float)(N_*P_);
        float m  = S * inv;
        float var = Q * inv - m*m;
        stats[c]      = m;
        stats[C_ + c] = rsqrtf(var + 1e-5f);
    }
}

__global__ __launch_bounds__(256) void bn_add_relu_kernel(
    const unsigned short* __restrict__ y2, const float* __restrict__ x,
    const float* __restrict__ stats,
    const float* __restrict__ gamma, const float* __restrict__ beta,
    float* __restrict__ out)
{
    size_t idx = (size_t)blockIdx.x*256 + threadIdx.x;
    int c = (int)((idx / P_) % C_);
    float v = (b2f(y2[idx]) - stats[c]) * stats[C_ + c] * gamma[c] + beta[c] + x[idx];
    out[idx] = fmaxf(v, 0.f);
}

// ---------------------------------------------------------------------------
extern "C" void kernel_launch(void* const* d_in, const int* in_sizes, int n_in,
                              void* d_out, int out_size, void* d_ws, size_t ws_size,
                              hipStream_t stream) {
    const float* x     = (const float*)d_in[0];
    const float* w_off = (const float*)d_in[1];
    const float* b_off = (const float*)d_in[2];
    const float* w1    = (const float*)d_in[3];
    const float* g1    = (const float*)d_in[4];
    const float* be1   = (const float*)d_in[5];
    const float* w2    = (const float*)d_in[6];
    const float* b2    = (const float*)d_in[7];
    const float* g2    = (const float*)d_in[8];
    const float* be2   = (const float*)d_in[9];
    float* out = (float*)d_out;

    // workspace (~88 MB)
    float* st1  = (float*)d_ws;                              // 128 (scale/shift)
    float* st2  = st1 + 128;                                 // 128 (mean/rstd)
    float* part = st2 + 128;                                 // 98*128
    unsigned short* off = (unsigned short*)(part + 98*128);  // N*648*P bf16 (65 MB)
    unsigned short* xt  = off + (size_t)N_*CO_OFF_*P_;       // N*P*64 bf16 (6.4 MB)
    unsigned short* y1t = xt  + (size_t)N_*P_*C_;            // N*P*64 bf16 (6.4 MB)
    unsigned short* y2  = y1t + (size_t)N_*P_*C_;            // N*64*P bf16 (6.4 MB)
    unsigned short* A1k = y2  + (size_t)N_*C_*P_;            // 768*1728 bf16 (2.65 MB)
    unsigned short* A1t = A1k + (size_t)MP_*KK_;             // 64*1728 bf16
    unsigned short* A2t = A1t + (size_t)C_*KK_;              // 64*1728 bf16

    // prep
    transpose_xt_kernel<<<N_*(P_/64), 256, 0, stream>>>(x, xt);
    permA1k_kernel<<<(MP_*KK_+255)/256, 256, 0, stream>>>(w_off, A1k);
    perm_w_kernel<<<(C_*KK_+255)/256, 256, 0, stream>>>(w1, A1t);
    perm_w_kernel<<<(C_*KK_+255)/256, 256, 0, stream>>>(w2, A2t);

    // conv_off fused -> off (both n): main (rows 0..639) + tail (640..647)
    conv_off_fused<<<2*980, 256, 0, stream>>>(A1k, xt, b_off, off);
    conv_off_tail<<<2*196, 256, 0, stream>>>(A1k, xt, b_off, off);

    // deform fused -> y1t (both n), register-B
    deform_fused<<<N_*(P_/64), 256, 0, stream>>>(xt, off, A1t, y1t);

    // BN1 scale/shift
    stats_partial_kernel<<<98, 256, 0, stream>>>(y1t, part);
    stats_final_kernel<<<1, 64, 0, stream>>>(part, g1, be1, st1);

    // conv2 fused (BN1+ReLU on read) -> y2 (both n), register-B
    conv2_fused<<<N_*(P_/64), 256, 0, stream>>>(y1t, st1, A2t, b2, y2);

    // BN2 + residual + ReLU -> out (fp32)
    bn_stats_kernel<<<C_, 256, 0, stream>>>(y2, st2);
    bn_add_relu_kernel<<<(N_*C_*P_)/256, 256, 0, stream>>>(y2, x, st2, g2, be2, out);
}

// Round 13
// 545.534 us; speedup vs baseline: 1.1156x; 1.1156x over previous
//
#include <hip/hip_runtime.h>
#include <hip/hip_bf16.h>

#define N_ 2
#define C_ 64
#define D_ 8
#define H_ 56
#define W_ 56
#define HW_ (H_*W_)        // 3136
#define P_ (D_*HW_)        // 25088
#define G_ 8
#define CPG_ 8
#define K_ 27
#define CO_OFF_ 648        // G * 3 * K
#define MP_ 768            // conv_off M padded (rows 648+ zero)
#define KK_ 1728           // GEMM K dim (= 27*64, k-major: ktap*64 + ci)
#define KB_ (KK_*2)        // bytes per bf16 row

typedef __attribute__((ext_vector_type(8))) short shortx8;
typedef __attribute__((ext_vector_type(4))) float floatx4;
#define AS1 __attribute__((address_space(1)))
#define AS3 __attribute__((address_space(3)))

__device__ inline float b2f(unsigned short u) {
    union { unsigned u; float f; } x; x.u = ((unsigned)u) << 16; return x.f;
}
__device__ inline unsigned short f2b(float f) {
    union { float f; unsigned u; } x; x.f = f;
    unsigned r = (x.u + 0x7fffu + ((x.u >> 16) & 1u)) >> 16;   // RNE
    return (unsigned short)r;
}
__device__ inline float lof(unsigned u) { union { unsigned u; float f; } x; x.u = u << 16; return x.f; }
__device__ inline float hif(unsigned u) { union { unsigned u; float f; } x; x.u = u & 0xffff0000u; return x.f; }

// off layout: off2[(g*27+kt)*P + p][3] bf16 (interleaved comps, 65 MB total)

// ---------------------------------------------------------------------------
// x [N][64][P] fp32 -> xt [N][P][64] bf16  (64p x 64c LDS tile transpose)
// ---------------------------------------------------------------------------
__global__ __launch_bounds__(256) void transpose_xt_kernel(
    const float* __restrict__ x, unsigned short* __restrict__ xt)
{
    __shared__ unsigned short tile[64][65];
    int b  = blockIdx.x;
    int n  = b / (P_/64);
    int p0 = (b % (P_/64))*64;
    int tid = threadIdx.x;
    int j  = tid & 63;
    int c0 = (tid >> 6)*16;
    for (int r = 0; r < 16; ++r)
        tile[c0 + r][j] = f2b(x[((size_t)n*C_ + c0 + r)*P_ + p0 + j]);
    __syncthreads();
    unsigned* dst = (unsigned*)(xt + ((size_t)n*P_ + p0)*C_);
    #pragma unroll
    for (int it = 0; it < 8; ++it) {
        int wi  = it*256 + tid;
        int row = wi >> 5;
        int c   = (wi & 31)*2;
        unsigned lo = tile[c][row], hi = tile[c+1][row];
        dst[(size_t)row*32 + (wi & 31)] = lo | (hi << 16);
    }
}

// w_off [648][64][27] fp32 -> A1k [768][kk*64+ci] bf16 (k-major, zero-pad rows)
__global__ __launch_bounds__(256) void permA1k_kernel(
    const float* __restrict__ w, unsigned short* __restrict__ A)
{
    int i = blockIdx.x*256 + threadIdx.x;
    if (i >= MP_*KK_) return;
    int m = i / KK_, r = i % KK_;
    int kk = r / 64, ci = r % 64;
    A[i] = (m < CO_OFF_) ? f2b(w[((size_t)m*C_ + ci)*K_ + kk]) : (unsigned short)0;
}

// w [O=64][I=64][27] fp32 -> At[o][k*64+i] bf16 (k-major)
__global__ __launch_bounds__(256) void perm_w_kernel(
    const float* __restrict__ w, unsigned short* __restrict__ At)
{
    int tid = blockIdx.x*256 + threadIdx.x;
    if (tid >= C_*KK_) return;
    int o  = tid / KK_;
    int r  = tid % KK_;
    int k  = r / 64, i = r % 64;
    At[tid] = f2b(w[((size_t)o*C_ + i)*K_ + k]);
}

// ---------------------------------------------------------------------------
// conv_off fused main: m-tiles 0..4 (rows 0..639). Pipelined (R9 structure).
// Epilogue scatters into interleaved off2 layout.
// ---------------------------------------------------------------------------
__global__ __launch_bounds__(256) void conv_off_fused(
    const unsigned short* __restrict__ A,    // A1k [768][1728]
    const unsigned short* __restrict__ xt,   // [N][P][64] bf16
    const float* __restrict__ bias,          // [648]
    unsigned short* __restrict__ off2)       // [N][216*P][3] bf16
{
    __shared__ __align__(16) short As[2][16*512];
    __shared__ __align__(16) short Bs[16*512];
    int tid = threadIdx.x;
    int w = tid >> 6, lane = tid & 63;
    int n   = blockIdx.x / 980;
    int bid = blockIdx.x % 980;
    int mt, nt;
    if (bid < 960) { int c = bid/40, r = bid%40; mt = r >> 3; nt = c*8 + (r&7); }
    else           { int r = bid - 960;          mt = r >> 2; nt = 192 + (r&3); }
    int m0 = mt*128, p0 = nt*128;
    int lm = lane & 15, lq = lane >> 4;

    const unsigned short* xtn = xt + (size_t)n*P_*C_;
    unsigned short* out2 = off2 + (size_t)n*216*P_*3;

    const char* Ab0 = (const char*)A + (size_t)(m0 + w*32 + lm)*KB_ + lq*16;
    const char* Ab1 = Ab0 + (size_t)16*KB_;

    int oct = lane & 7;
    int prj[4], dj[4], hj[4], wj[4];
    #pragma unroll
    for (int j = 0; j < 4; ++j) {
        int prow = j*32 + w*8 + (lane >> 3);
        prj[j] = prow;
        int p = p0 + prow;
        dj[j] = p / HW_;
        int hw2 = p % HW_;
        hj[j] = hw2 / W_;
        wj[j] = hw2 % W_;
    }

    auto stageA = [&](int kt, int buf) {
        __builtin_amdgcn_global_load_lds((const AS1 unsigned*)(Ab0 + kt*128),      (AS3 unsigned*)(&As[buf][(w*2)*512]),     16, 0, 0);
        __builtin_amdgcn_global_load_lds((const AS1 unsigned*)(Ab1 + kt*128),      (AS3 unsigned*)(&As[buf][(w*2+1)*512]),   16, 0, 0);
        __builtin_amdgcn_global_load_lds((const AS1 unsigned*)(Ab0 + kt*128 + 64), (AS3 unsigned*)(&As[buf][(8+w*2)*512]),   16, 0, 0);
        __builtin_amdgcn_global_load_lds((const AS1 unsigned*)(Ab1 + kt*128 + 64), (AS3 unsigned*)(&As[buf][(8+w*2+1)*512]), 16, 0, 0);
    };
    auto loadB = [&](int kt, uint4* B) {
        int kd = kt/9 - 1, kh = (kt/3)%3 - 1, kw = kt%3 - 1;
        int delta = kd*HW_ + kh*W_ + kw;
        #pragma unroll
        for (int j = 0; j < 4; ++j) {
            bool v = ((unsigned)(dj[j]+kd) < (unsigned)D_) &&
                     ((unsigned)(hj[j]+kh) < (unsigned)H_) &&
                     ((unsigned)(wj[j]+kw) < (unsigned)W_);
            uint4 val = {0u,0u,0u,0u};
            if (v) val = *(const uint4*)(xtn + (size_t)(p0 + prj[j] + delta)*C_ + oct*8);
            B[j] = val;
        }
    };

    int mh = w >> 1, nh = w & 1;
    floatx4 acc[4][4];
    #pragma unroll
    for (int i = 0; i < 4; ++i)
        #pragma unroll
        for (int j = 0; j < 4; ++j)
            acc[i][j] = (floatx4){0.f, 0.f, 0.f, 0.f};

    uint4 Bcur[4], Bnext[4];
    #pragma unroll
    for (int j = 0; j < 4; ++j) Bnext[j] = (uint4){0u,0u,0u,0u};
    stageA(0, 0);
    loadB(0, Bcur);

    for (int kt = 0; kt < 27; ++kt) {
        int buf = kt & 1;
        __syncthreads();
        #pragma unroll
        for (int j = 0; j < 4; ++j) {
            int chunk = (oct>>2)*8 + (prj[j]>>4);
            *(uint4*)&Bs[chunk*512 + ((oct&3)*16 + ((prj[j]&15) ^ oct))*8] = Bcur[j];
        }
        __syncthreads();
        if (kt < 26) { stageA(kt+1, buf^1); loadB(kt+1, Bnext); }
        #pragma unroll
        for (int ks = 0; ks < 2; ++ks) {
            int swzB = (lq*16 + (lm ^ (ks*4 + lq)))*8;
            shortx8 a[4], b[4];
            #pragma unroll
            for (int i = 0; i < 4; ++i) a[i] = *(const shortx8*)&As[buf][(ks*8 + 4*mh + i)*512 + lane*8];
            #pragma unroll
            for (int j = 0; j < 4; ++j) b[j] = *(const shortx8*)&Bs[(ks*8 + 4*nh + j)*512 + swzB];
            #pragma unroll
            for (int i = 0; i < 4; ++i)
                #pragma unroll
                for (int j = 0; j < 4; ++j)
                    acc[i][j] = __builtin_amdgcn_mfma_f32_16x16x32_bf16(a[i], b[j], acc[i][j], 0, 0, 0);
        }
        #pragma unroll
        for (int j = 0; j < 4; ++j) Bcur[j] = Bnext[j];
    }

    #pragma unroll
    for (int i = 0; i < 4; ++i) {
        int cob = m0 + (4*mh+i)*16 + lq*4;
        #pragma unroll
        for (int r = 0; r < 4; ++r) {
            int co = cob + r;    // < 640 always (mt <= 4)
            float bv = bias[co];
            int row2 = co / 3, comp = co % 3;
            size_t base = (size_t)row2*P_*3 + comp;
            #pragma unroll
            for (int j = 0; j < 4; ++j) {
                int col = p0 + (4*nh+j)*16 + lm;
                out2[base + (size_t)col*3] = f2b(acc[i][j][r] + bv);
            }
        }
    }
}

// ---------------------------------------------------------------------------
// conv_off tail: rows 640..655 (648..655 zero-padded). 16x128 tile.
// ---------------------------------------------------------------------------
__global__ __launch_bounds__(256) void conv_off_tail(
    const unsigned short* __restrict__ A,    // A1k [768][1728]
    const unsigned short* __restrict__ xt,   // [N][P][64] bf16
    const float* __restrict__ bias,          // [648]
    unsigned short* __restrict__ off2)       // [N][216*P][3] bf16
{
    __shared__ __align__(16) short As[54*512];
    __shared__ __align__(16) short Bs[16*512];
    int tid = threadIdx.x;
    int w = tid >> 6, lane = tid & 63;
    int n  = blockIdx.x / 196;
    int p0 = (blockIdx.x % 196)*128;
    int lm = lane & 15, lq = lane >> 4;

    const unsigned short* xtn = xt + (size_t)n*P_*C_;
    unsigned short* out2 = off2 + (size_t)n*216*P_*3;

    const char* Abase = (const char*)A + (size_t)(640 + lm)*KB_ + lq*16;
    for (int ch = w; ch < 54; ch += 4)
        __builtin_amdgcn_global_load_lds((const AS1 unsigned*)(Abase + ch*64),
                                         (AS3 unsigned*)(As + ch*512), 16, 0, 0);

    int oct = lane & 7;
    int prj[4], dj[4], hj[4], wj[4];
    #pragma unroll
    for (int j = 0; j < 4; ++j) {
        int prow = j*32 + w*8 + (lane >> 3);
        prj[j] = prow;
        int p = p0 + prow;
        dj[j] = p / HW_;
        int hw2 = p % HW_;
        hj[j] = hw2 / W_;
        wj[j] = hw2 % W_;
    }
    auto loadB = [&](int kt, uint4* B) {
        int kd = kt/9 - 1, kh = (kt/3)%3 - 1, kw = kt%3 - 1;
        int delta = kd*HW_ + kh*W_ + kw;
        #pragma unroll
        for (int j = 0; j < 4; ++j) {
            bool v = ((unsigned)(dj[j]+kd) < (unsigned)D_) &&
                     ((unsigned)(hj[j]+kh) < (unsigned)H_) &&
                     ((unsigned)(wj[j]+kw) < (unsigned)W_);
            uint4 val = {0u,0u,0u,0u};
            if (v) val = *(const uint4*)(xtn + (size_t)(p0 + prj[j] + delta)*C_ + oct*8);
            B[j] = val;
        }
    };

    floatx4 acc[2];
    acc[0] = (floatx4){0.f,0.f,0.f,0.f};
    acc[1] = (floatx4){0.f,0.f,0.f,0.f};

    uint4 Bcur[4], Bnext[4];
    #pragma unroll
    for (int j = 0; j < 4; ++j) Bnext[j] = (uint4){0u,0u,0u,0u};
    loadB(0, Bcur);

    for (int kt = 0; kt < 27; ++kt) {
        __syncthreads();
        #pragma unroll
        for (int j = 0; j < 4; ++j) {
            int chunk = (oct>>2)*8 + (prj[j]>>4);
            *(uint4*)&Bs[chunk*512 + ((oct&3)*16 + ((prj[j]&15) ^ oct))*8] = Bcur[j];
        }
        __syncthreads();
        if (kt < 26) loadB(kt+1, Bnext);
        #pragma unroll
        for (int ks = 0; ks < 2; ++ks) {
            int swzB = (lq*16 + (lm ^ (ks*4 + lq)))*8;
            shortx8 a = *(const shortx8*)&As[(kt*2 + ks)*512 + lane*8];
            #pragma unroll
            for (int j = 0; j < 2; ++j) {
                shortx8 b = *(const shortx8*)&Bs[(ks*8 + w*2 + j)*512 + swzB];
                acc[j] = __builtin_amdgcn_mfma_f32_16x16x32_bf16(a, b, acc[j], 0, 0, 0);
            }
        }
        #pragma unroll
        for (int j = 0; j < 4; ++j) Bcur[j] = Bnext[j];
    }

    #pragma unroll
    for (int j = 0; j < 2; ++j) {
        #pragma unroll
        for (int r = 0; r < 4; ++r) {
            int co = 640 + lq*4 + r;
            if (co < CO_OFF_) {
                int col = p0 + w*32 + j*16 + lm;
                out2[((size_t)(co/3)*P_ + col)*3 + (co%3)] = f2b(acc[j][r] + bias[co]);
            }
        }
    }
}

// ---------------------------------------------------------------------------
// deform fused (R11 structure): N=32 tiles, LDS-B, 2-deep pipeline; off reads
// now hit ONE cache line per task (interleaved off2 layout).
// ---------------------------------------------------------------------------
__global__ __launch_bounds__(256) void deform_fused(
    const unsigned short* __restrict__ xt,   // [N][P][64] bf16
    const unsigned short* __restrict__ off2, // [N][216*P][3] bf16
    const unsigned short* __restrict__ A,    // A1t [64][1728]
    unsigned short* __restrict__ y1t)        // [N][P][64] bf16
{
    __shared__ __align__(16) short SH[10240]; // As dbuf 2x4096, Bs 2048
    short* Bsb = SH + 8192;
    int tid = threadIdx.x;
    int w = tid >> 6, lane = tid & 63;
    int n  = blockIdx.x / (P_/32);
    int p0 = (blockIdx.x % (P_/32))*32;
    int lm = lane & 15, lq = lane >> 4;

    const unsigned short* offn = off2 + (size_t)n*216*P_*3;
    const uint4* xg0 = (const uint4*)(xt + (size_t)n*P_*C_);

    const char* Ab = (const char*)A + (size_t)(w*16 + lm)*KB_ + lq*16;

    int g = lane & 7;
    int prow = tid >> 3;          // 0..31
    int p = p0 + prow;
    int dd = p / HW_;
    int hw2 = p % HW_;
    int hh = hw2 / W_;
    int ww = hw2 % W_;

    auto stageA = [&](int kt, int buf) {
        __builtin_amdgcn_global_load_lds((const AS1 unsigned*)(Ab + kt*128),      (AS3 unsigned*)(SH + buf*4096 + w*512),     16, 0, 0);
        __builtin_amdgcn_global_load_lds((const AS1 unsigned*)(Ab + kt*128 + 64), (AS3 unsigned*)(SH + buf*4096 + (4+w)*512), 16, 0, 0);
    };
    auto loadOff = [&](int kt, float* o) {
        size_t idx = ((size_t)(g*K_ + kt)*P_ + p)*3;   // one line for 8-lane group
        o[0] = b2f(offn[idx]);
        o[1] = b2f(offn[idx + 1]);
        o[2] = b2f(offn[idx + 2]);
    };
    auto issueCorners = [&](int kt, float* o, uint4* V, float* Wt) {
        int kd = kt/9 - 1, kh = (kt/3)%3 - 1, kw = kt%3 - 1;
        float pd = (float)(dd + kd) + o[0];
        float ph = (float)(hh + kh) + o[1];
        float pw = (float)(ww + kw) + o[2];
        float fd0 = floorf(pd), fh0 = floorf(ph), fw0 = floorf(pw);
        int d0 = (int)fd0, h0 = (int)fh0, w0i = (int)fw0;
        float fd = pd - fd0, fh = ph - fh0, fw = pw - fw0;
        int idx = 0;
        #pragma unroll
        for (int cd = 0; cd < 2; ++cd) {
            int id = d0 + cd;
            float wdt = cd ? fd : 1.f - fd;
            bool vdd = (unsigned)id < (unsigned)D_;
            int idc = min(max(id, 0), D_-1);
            #pragma unroll
            for (int ch = 0; ch < 2; ++ch) {
                int ih = h0 + ch;
                float wht = ch ? fh : 1.f - fh;
                bool vhh = (unsigned)ih < (unsigned)H_;
                int ihc = min(max(ih, 0), H_-1);
                #pragma unroll
                for (int cw = 0; cw < 2; ++cw) {
                    int iw = w0i + cw;
                    float wwt = cw ? fw : 1.f - fw;
                    bool vww = (unsigned)iw < (unsigned)W_;
                    int iwc = min(max(iw, 0), W_-1);
                    int lin = (idc*H_ + ihc)*W_ + iwc;
                    V[idx]  = xg0[(size_t)lin*(C_/8) + g];
                    Wt[idx] = (vdd && vhh && vww) ? wdt*wht*wwt : 0.f;
                    ++idx;
                }
            }
        }
    };
    auto reduceCorners = [&](uint4* V, float* Wt, uint4& o4) {
        float res[CPG_];
        #pragma unroll
        for (int c = 0; c < CPG_; ++c) res[c] = 0.f;
        #pragma unroll
        for (int c = 0; c < 8; ++c) {
            uint4 v4 = V[c];
            float wgt = Wt[c];
            res[0] = fmaf(wgt, lof(v4.x), res[0]);
            res[1] = fmaf(wgt, hif(v4.x), res[1]);
            res[2] = fmaf(wgt, lof(v4.y), res[2]);
            res[3] = fmaf(wgt, hif(v4.y), res[3]);
            res[4] = fmaf(wgt, lof(v4.z), res[4]);
            res[5] = fmaf(wgt, hif(v4.z), res[5]);
            res[6] = fmaf(wgt, lof(v4.w), res[6]);
            res[7] = fmaf(wgt, hif(v4.w), res[7]);
        }
        o4.x = (unsigned)f2b(res[0]) | ((unsigned)f2b(res[1]) << 16);
        o4.y = (unsigned)f2b(res[2]) | ((unsigned)f2b(res[3]) << 16);
        o4.z = (unsigned)f2b(res[4]) | ((unsigned)f2b(res[5]) << 16);
        o4.w = (unsigned)f2b(res[6]) | ((unsigned)f2b(res[7]) << 16);
    };

    int mh = w >> 1, nh = w & 1;
    floatx4 acc[2];
    acc[0] = (floatx4){0.f,0.f,0.f,0.f};
    acc[1] = (floatx4){0.f,0.f,0.f,0.f};

    float offA[3], offB[3], offT[3];
    uint4 Vv[8]; float Wt[8];
    uint4 o4cur;

    stageA(0, 0);
    loadOff(0, offA);
    loadOff(1, offB);
    issueCorners(0, offA, Vv, Wt);
    reduceCorners(Vv, Wt, o4cur);

    for (int kt = 0; kt < 27; ++kt) {
        int buf = kt & 1;
        __syncthreads();
        {
            int chunk = (g>>2)*2 + (prow>>4);
            *(uint4*)&Bsb[chunk*512 + ((g&3)*16 + ((prow&15) ^ g))*8] = o4cur;
        }
        __syncthreads();
        if (kt < 26) {
            stageA(kt+1, buf^1);
            if (kt < 25) loadOff(kt+2, offT);
            issueCorners(kt+1, offB, Vv, Wt);
        }
        #pragma unroll
        for (int ks = 0; ks < 2; ++ks) {
            int swzB = (lq*16 + (lm ^ (ks*4 + lq)))*8;
            shortx8 b = *(const shortx8*)&Bsb[(ks*2 + nh)*512 + swzB];
            #pragma unroll
            for (int i = 0; i < 2; ++i) {
                shortx8 a = *(const shortx8*)&SH[buf*4096 + (ks*4 + 2*mh+i)*512 + lane*8];
                acc[i] = __builtin_amdgcn_mfma_f32_16x16x32_bf16(a, b, acc[i], 0, 0, 0);
            }
        }
        if (kt < 26) {
            reduceCorners(Vv, Wt, o4cur);
            offB[0] = offT[0]; offB[1] = offT[1]; offB[2] = offT[2];
        }
    }

    // epilogue: transpose 64o x 32p tile to y1t[p][o] via LDS (stride 72)
    __syncthreads();
    #pragma unroll
    for (int i = 0; i < 2; ++i) {
        int ob = mh*32 + i*16 + lq*4;
        int pc = nh*16 + lm;
        #pragma unroll
        for (int rr = 0; rr < 4; ++rr)
            SH[pc*72 + ob + rr] = (short)f2b(acc[i][rr]);
    }
    __syncthreads();
    {
        int row = tid >> 3, seg = tid & 7;
        uint4 v = *(const uint4*)&SH[row*72 + seg*8];
        *(uint4*)(y1t + ((size_t)n*P_ + p0 + row)*C_ + seg*8) = v;
    }
}

// ---------------------------------------------------------------------------
// conv2 fused (R12 register-B version): lane's B-frag = one masked 16B load
// + BN+ReLU+pack (V[2] = 8 VGPRs -> compiler keeps the prefetch).
// ---------------------------------------------------------------------------
__global__ __launch_bounds__(256) void conv2_fused(
    const unsigned short* __restrict__ y1t,  // [N][P][64] bf16
    const float* __restrict__ st1,           // [64] scale, [64] shift
    const unsigned short* __restrict__ A,    // A2t [64][1728]
    const float* __restrict__ bias,          // [64]
    unsigned short* __restrict__ y2)         // [N][64][P] bf16
{
    __shared__ __align__(16) short As[2][4096];
    __shared__ float sc[64], sf[64];
    int tid = threadIdx.x;
    if (tid < 64) sc[tid] = st1[tid];
    else if (tid < 128) sf[tid-64] = st1[tid];
    int w = tid >> 6, lane = tid & 63;
    int n  = blockIdx.x / (P_/64);
    int p0 = (blockIdx.x % (P_/64))*64;
    int lm = lane & 15, lq = lane >> 4;

    const unsigned short* y1n = y1t + (size_t)n*P_*C_;
    unsigned short* y2n = y2 + (size_t)n*C_*P_;
    const char* Ab = (const char*)A + (size_t)(w*16 + lm)*KB_ + lq*16;

    int p = p0 + w*16 + lm;
    int dd = p / HW_, hw2 = p % HW_;
    int hh = hw2 / W_, ww = hw2 % W_;

    auto stageA = [&](int kt, int buf) {
        __builtin_amdgcn_global_load_lds((const AS1 unsigned*)(Ab + kt*128),      (AS3 unsigned*)(&As[buf][w*512]),     16, 0, 0);
        __builtin_amdgcn_global_load_lds((const AS1 unsigned*)(Ab + kt*128 + 64), (AS3 unsigned*)(&As[buf][(4+w)*512]), 16, 0, 0);
    };
    auto issueV = [&](int kt, uint4* V, int& M) {
        int kd = kt/9 - 1, kh = (kt/3)%3 - 1, kw = kt%3 - 1;
        int delta = kd*HW_ + kh*W_ + kw;
        bool v = ((unsigned)(dd+kd) < (unsigned)D_) &&
                 ((unsigned)(hh+kh) < (unsigned)H_) &&
                 ((unsigned)(ww+kw) < (unsigned)W_);
        M = v ? 1 : 0;
        #pragma unroll
        for (int ks = 0; ks < 2; ++ks) {
            uint4 val = {0u,0u,0u,0u};
            if (v) val = *(const uint4*)(y1n + (size_t)(p + delta)*C_ + (ks*4 + lq)*8);
            V[ks] = val;
        }
    };
    auto reduceT = [&](uint4 V, int ks, int M) -> shortx8 {
        uint4 o4 = {0u,0u,0u,0u};
        if (M) {
            int cb = (ks*4 + lq)*8;
            float r0 = fmaxf(lof(V.x)*sc[cb+0] + sf[cb+0], 0.f);
            float r1 = fmaxf(hif(V.x)*sc[cb+1] + sf[cb+1], 0.f);
            float r2 = fmaxf(lof(V.y)*sc[cb+2] + sf[cb+2], 0.f);
            float r3 = fmaxf(hif(V.y)*sc[cb+3] + sf[cb+3], 0.f);
            float r4 = fmaxf(lof(V.z)*sc[cb+4] + sf[cb+4], 0.f);
            float r5 = fmaxf(hif(V.z)*sc[cb+5] + sf[cb+5], 0.f);
            float r6 = fmaxf(lof(V.w)*sc[cb+6] + sf[cb+6], 0.f);
            float r7 = fmaxf(hif(V.w)*sc[cb+7] + sf[cb+7], 0.f);
            o4.x = (unsigned)f2b(r0) | ((unsigned)f2b(r1) << 16);
            o4.y = (unsigned)f2b(r2) | ((unsigned)f2b(r3) << 16);
            o4.z = (unsigned)f2b(r4) | ((unsigned)f2b(r5) << 16);
            o4.w = (unsigned)f2b(r6) | ((unsigned)f2b(r7) << 16);
        }
        return *(shortx8*)&o4;
    };

    floatx4 acc[4];
    #pragma unroll
    for (int i = 0; i < 4; ++i) acc[i] = (floatx4){0.f,0.f,0.f,0.f};

    uint4 V[2];
    int M;
    stageA(0, 0);
    issueV(0, V, M);

    for (int kt = 0; kt < 27; ++kt) {
        int buf = kt & 1;
        __syncthreads();                     // also makes sc/sf visible (kt=0)
        if (kt < 26) stageA(kt+1, buf^1);
        shortx8 b0 = reduceT(V[0], 0, M);
        shortx8 b1 = reduceT(V[1], 1, M);
        if (kt < 26) issueV(kt+1, V, M);
        #pragma unroll
        for (int i = 0; i < 4; ++i) {
            shortx8 a = *(const shortx8*)&As[buf][(0*4 + i)*512 + lane*8];
            acc[i] = __builtin_amdgcn_mfma_f32_16x16x32_bf16(a, b0, acc[i], 0, 0, 0);
        }
        #pragma unroll
        for (int i = 0; i < 4; ++i) {
            shortx8 a = *(const shortx8*)&As[buf][(1*4 + i)*512 + lane*8];
            acc[i] = __builtin_amdgcn_mfma_f32_16x16x32_bf16(a, b1, acc[i], 0, 0, 0);
        }
    }

    #pragma unroll
    for (int i = 0; i < 4; ++i) {
        #pragma unroll
        for (int r = 0; r < 4; ++r) {
            int co = i*16 + lq*4 + r;
            y2n[(size_t)co*P_ + p] = f2b(acc[i][r] + bias[co]);
        }
    }
}

// ---------------------------------------------------------------------------
// BN1 stats from y1t [N*P][64]: partial sums per 512-row block, then finalize
// ---------------------------------------------------------------------------
__global__ __launch_bounds__(256) void stats_partial_kernel(
    const unsigned short* __restrict__ y1t, float* __restrict__ part)
{
    int b = blockIdx.x, tid = threadIdx.x;
    int c = tid & 63, sub = tid >> 6;
    float s = 0.f, q = 0.f;
    for (int rr = 0; rr < 128; ++rr) {
        int row = b*512 + sub*128 + rr;
        float v = b2f(y1t[(size_t)row*C_ + c]);
        s += v;
        q = fmaf(v, v, q);
    }
    __shared__ float ss[256], qq[256];
    ss[tid] = s; qq[tid] = q;
    __syncthreads();
    if (tid < 64) {
        float S = ss[tid] + ss[64+tid] + ss[128+tid] + ss[192+tid];
        float Q = qq[tid] + qq[64+tid] + qq[128+tid] + qq[192+tid];
        part[b*128 + tid]      = S;
        part[b*128 + 64 + tid] = Q;
    }
}

__global__ void stats_final_kernel(
    const float* __restrict__ part,
    const float* __restrict__ gamma, const float* __restrict__ beta,
    float* __restrict__ st1)
{
    int c = threadIdx.x;  // 64 threads
    float S = 0.f, Q = 0.f;
    for (int b = 0; b < 98; ++b) {
        S += part[b*128 + c];
        Q += part[b*128 + 64 + c];
    }
    const float inv = 1.f / (float)(N_*P_);
    float m = S * inv;
    float var = Q * inv - m*m;
    float scale = rsqrtf(var + 1e-5f) * gamma[c];
    st1[c]      = scale;
    st1[64 + c] = beta[c] - m*scale;
}

// ---------------------------------------------------------------------------
__global__ __launch_bounds__(256) void bn_stats_kernel(
    const unsigned short* __restrict__ src, float* __restrict__ stats)
{
    int c   = blockIdx.x;
    int tid = threadIdx.x;
    float s = 0.f, q = 0.f;
    for (int n = 0; n < N_; ++n) {
        const unsigned short* p = src + ((size_t)n*C_ + c)*P_;
        for (int i = tid; i < P_; i += 256) {
            float v = b2f(p[i]);
            s += v;
            q = fmaf(v, v, q);
        }
    }
    #pragma unroll
    for (int o = 32; o; o >>= 1) {
        s += __shfl_down(s, o);
        q += __shfl_down(q, o);
    }
    __shared__ float sh[2][4];
    int wave = tid >> 6;
    if ((tid & 63) == 0) { sh[0][wave] = s; sh[1][wave] = q; }
    __syncthreads();
    if (tid == 0) {
        float S = sh[0][0] + sh[0][1] + sh[0][2] + sh[0][3];
        float Q = sh[1][0] + sh[1][1] + sh[1][2] + sh[1][3];
        const float inv = 1.f / (float)(N_*P_);
        float m  = S * inv;
        float var = Q * inv - m*m;
        stats[c]      = m;
        stats[C_ + c] = rsqrtf(var + 1e-5f);
    }
}

__global__ __launch_bounds__(256) void bn_add_relu_kernel(
    const unsigned short* __restrict__ y2, const float* __restrict__ x,
    const float* __restrict__ stats,
    const float* __restrict__ gamma, const float* __restrict__ beta,
    float* __restrict__ out)
{
    size_t idx = (size_t)blockIdx.x*256 + threadIdx.x;
    int c = (int)((idx / P_) % C_);
    float v = (b2f(y2[idx]) - stats[c]) * stats[C_ + c] * gamma[c] + beta[c] + x[idx];
    out[idx] = fmaxf(v, 0.f);
}

// ---------------------------------------------------------------------------
extern "C" void kernel_launch(void* const* d_in, const int* in_sizes, int n_in,
                              void* d_out, int out_size, void* d_ws, size_t ws_size,
                              hipStream_t stream) {
    const float* x     = (const float*)d_in[0];
    const float* w_off = (const float*)d_in[1];
    const float* b_off = (const float*)d_in[2];
    const float* w1    = (const float*)d_in[3];
    const float* g1    = (const float*)d_in[4];
    const float* be1   = (const float*)d_in[5];
    const float* w2    = (const float*)d_in[6];
    const float* b2    = (const float*)d_in[7];
    const float* g2    = (const float*)d_in[8];
    const float* be2   = (const float*)d_in[9];
    float* out = (float*)d_out;

    // workspace (~88 MB)
    float* st1  = (float*)d_ws;                              // 128 (scale/shift)
    float* st2  = st1 + 128;                                 // 128 (mean/rstd)
    float* part = st2 + 128;                                 // 98*128
    unsigned short* off2 = (unsigned short*)(part + 98*128); // N*216*P*3 bf16 (65 MB)
    unsigned short* xt  = off2 + (size_t)N_*216*P_*3;        // N*P*64 bf16 (6.4 MB)
    unsigned short* y1t = xt  + (size_t)N_*P_*C_;            // N*P*64 bf16 (6.4 MB)
    unsigned short* y2  = y1t + (size_t)N_*P_*C_;            // N*64*P bf16 (6.4 MB)
    unsigned short* A1k = y2  + (size_t)N_*C_*P_;            // 768*1728 bf16 (2.65 MB)
    unsigned short* A1t = A1k + (size_t)MP_*KK_;             // 64*1728 bf16
    unsigned short* A2t = A1t + (size_t)C_*KK_;              // 64*1728 bf16

    // prep
    transpose_xt_kernel<<<N_*(P_/64), 256, 0, stream>>>(x, xt);
    permA1k_kernel<<<(MP_*KK_+255)/256, 256, 0, stream>>>(w_off, A1k);
    perm_w_kernel<<<(C_*KK_+255)/256, 256, 0, stream>>>(w1, A1t);
    perm_w_kernel<<<(C_*KK_+255)/256, 256, 0, stream>>>(w2, A2t);

    // conv_off fused -> off2 (both n): main (rows 0..639) + tail (640..647)
    conv_off_fused<<<2*980, 256, 0, stream>>>(A1k, xt, b_off, off2);
    conv_off_tail<<<2*196, 256, 0, stream>>>(A1k, xt, b_off, off2);

    // deform fused -> y1t (both n), N=32 tiles, interleaved off reads
    deform_fused<<<N_*(P_/32), 256, 0, stream>>>(xt, off2, A1t, y1t);

    // BN1 scale/shift
    stats_partial_kernel<<<98, 256, 0, stream>>>(y1t, part);
    stats_final_kernel<<<1, 64, 0, stream>>>(part, g1, be1, st1);

    // conv2 fused (BN1+ReLU on read) -> y2 (both n), register-B
    conv2_fused<<<N_*(P_/64), 256, 0, stream>>>(y1t, st1, A2t, b2, y2);

    // BN2 + residual + ReLU -> out (fp32)
    bn_stats_kernel<<<C_, 256, 0, stream>>>(y2, st2);
    bn_add_relu_kernel<<<(N_*C_*P_)/256, 256, 0, stream>>>(y2, x, st2, g2, be2, out);
}

// Round 14
// 543.760 us; speedup vs baseline: 1.1193x; 1.0033x over previous
//
#include <hip/hip_runtime.h>
#include <hip/hip_bf16.h>

#define N_ 2
#define C_ 64
#define D_ 8
#define H_ 56
#define W_ 56
#define HW_ (H_*W_)        // 3136
#define P_ (D_*HW_)        // 25088
#define G_ 8
#define CPG_ 8
#define K_ 27
#define CO_OFF_ 648        // G * 3 * K
#define MP_ 768            // conv_off M padded (rows 648+ zero)
#define KK_ 1728           // GEMM K dim (= 27*64, k-major: ktap*64 + ci)
#define KB_ (KK_*2)        // bytes per bf16 row

typedef __attribute__((ext_vector_type(8))) short shortx8;
typedef __attribute__((ext_vector_type(4))) float floatx4;
#define AS1 __attribute__((address_space(1)))
#define AS3 __attribute__((address_space(3)))

__device__ inline float b2f(unsigned short u) {
    union { unsigned u; float f; } x; x.u = ((unsigned)u) << 16; return x.f;
}
__device__ inline unsigned short f2b(float f) {
    union { float f; unsigned u; } x; x.f = f;
    unsigned r = (x.u + 0x7fffu + ((x.u >> 16) & 1u)) >> 16;   // RNE
    return (unsigned short)r;
}
__device__ inline float lof(unsigned u) { union { unsigned u; float f; } x; x.u = u << 16; return x.f; }
__device__ inline float hif(unsigned u) { union { unsigned u; float f; } x; x.u = u & 0xffff0000u; return x.f; }

// off layout: off2[(g*27+kt)*P + p][3] bf16 (interleaved comps, 65 MB total)

// ---------------------------------------------------------------------------
// x [N][64][P] fp32 -> xt [N][P][64] bf16  (64p x 64c LDS tile transpose)
// ---------------------------------------------------------------------------
__global__ __launch_bounds__(256) void transpose_xt_kernel(
    const float* __restrict__ x, unsigned short* __restrict__ xt)
{
    __shared__ unsigned short tile[64][65];
    int b  = blockIdx.x;
    int n  = b / (P_/64);
    int p0 = (b % (P_/64))*64;
    int tid = threadIdx.x;
    int j  = tid & 63;
    int c0 = (tid >> 6)*16;
    for (int r = 0; r < 16; ++r)
        tile[c0 + r][j] = f2b(x[((size_t)n*C_ + c0 + r)*P_ + p0 + j]);
    __syncthreads();
    unsigned* dst = (unsigned*)(xt + ((size_t)n*P_ + p0)*C_);
    #pragma unroll
    for (int it = 0; it < 8; ++it) {
        int wi  = it*256 + tid;
        int row = wi >> 5;
        int c   = (wi & 31)*2;
        unsigned lo = tile[c][row], hi = tile[c+1][row];
        dst[(size_t)row*32 + (wi & 31)] = lo | (hi << 16);
    }
}

// w_off [648][64][27] fp32 -> A1k [768][kk*64+ci] bf16 (k-major, zero-pad rows)
__global__ __launch_bounds__(256) void permA1k_kernel(
    const float* __restrict__ w, unsigned short* __restrict__ A)
{
    int i = blockIdx.x*256 + threadIdx.x;
    if (i >= MP_*KK_) return;
    int m = i / KK_, r = i % KK_;
    int kk = r / 64, ci = r % 64;
    A[i] = (m < CO_OFF_) ? f2b(w[((size_t)m*C_ + ci)*K_ + kk]) : (unsigned short)0;
}

// w [O=64][I=64][27] fp32 -> At[o][k*64+i] bf16 (k-major)
__global__ __launch_bounds__(256) void perm_w_kernel(
    const float* __restrict__ w, unsigned short* __restrict__ At)
{
    int tid = blockIdx.x*256 + threadIdx.x;
    if (tid >= C_*KK_) return;
    int o  = tid / KK_;
    int r  = tid % KK_;
    int k  = r / 64, i = r % 64;
    At[tid] = f2b(w[((size_t)o*C_ + i)*K_ + k]);
}

// ---------------------------------------------------------------------------
// conv_off fused main: m-tiles 0..4 (rows 0..639). Pipelined (R9 structure).
// ---------------------------------------------------------------------------
__global__ __launch_bounds__(256) void conv_off_fused(
    const unsigned short* __restrict__ A,    // A1k [768][1728]
    const unsigned short* __restrict__ xt,   // [N][P][64] bf16
    const float* __restrict__ bias,          // [648]
    unsigned short* __restrict__ off2)       // [N][216*P][3] bf16
{
    __shared__ __align__(16) short As[2][16*512];
    __shared__ __align__(16) short Bs[16*512];
    int tid = threadIdx.x;
    int w = tid >> 6, lane = tid & 63;
    int n   = blockIdx.x / 980;
    int bid = blockIdx.x % 980;
    int mt, nt;
    if (bid < 960) { int c = bid/40, r = bid%40; mt = r >> 3; nt = c*8 + (r&7); }
    else           { int r = bid - 960;          mt = r >> 2; nt = 192 + (r&3); }
    int m0 = mt*128, p0 = nt*128;
    int lm = lane & 15, lq = lane >> 4;

    const unsigned short* xtn = xt + (size_t)n*P_*C_;
    unsigned short* out2 = off2 + (size_t)n*216*P_*3;

    const char* Ab0 = (const char*)A + (size_t)(m0 + w*32 + lm)*KB_ + lq*16;
    const char* Ab1 = Ab0 + (size_t)16*KB_;

    int oct = lane & 7;
    int prj[4], dj[4], hj[4], wj[4];
    #pragma unroll
    for (int j = 0; j < 4; ++j) {
        int prow = j*32 + w*8 + (lane >> 3);
        prj[j] = prow;
        int p = p0 + prow;
        dj[j] = p / HW_;
        int hw2 = p % HW_;
        hj[j] = hw2 / W_;
        wj[j] = hw2 % W_;
    }

    auto stageA = [&](int kt, int buf) {
        __builtin_amdgcn_global_load_lds((const AS1 unsigned*)(Ab0 + kt*128),      (AS3 unsigned*)(&As[buf][(w*2)*512]),     16, 0, 0);
        __builtin_amdgcn_global_load_lds((const AS1 unsigned*)(Ab1 + kt*128),      (AS3 unsigned*)(&As[buf][(w*2+1)*512]),   16, 0, 0);
        __builtin_amdgcn_global_load_lds((const AS1 unsigned*)(Ab0 + kt*128 + 64), (AS3 unsigned*)(&As[buf][(8+w*2)*512]),   16, 0, 0);
        __builtin_amdgcn_global_load_lds((const AS1 unsigned*)(Ab1 + kt*128 + 64), (AS3 unsigned*)(&As[buf][(8+w*2+1)*512]), 16, 0, 0);
    };
    auto loadB = [&](int kt, uint4* B) {
        int kd = kt/9 - 1, kh = (kt/3)%3 - 1, kw = kt%3 - 1;
        int delta = kd*HW_ + kh*W_ + kw;
        #pragma unroll
        for (int j = 0; j < 4; ++j) {
            bool v = ((unsigned)(dj[j]+kd) < (unsigned)D_) &&
                     ((unsigned)(hj[j]+kh) < (unsigned)H_) &&
                     ((unsigned)(wj[j]+kw) < (unsigned)W_);
            uint4 val = {0u,0u,0u,0u};
            if (v) val = *(const uint4*)(xtn + (size_t)(p0 + prj[j] + delta)*C_ + oct*8);
            B[j] = val;
        }
    };

    int mh = w >> 1, nh = w & 1;
    floatx4 acc[4][4];
    #pragma unroll
    for (int i = 0; i < 4; ++i)
        #pragma unroll
        for (int j = 0; j < 4; ++j)
            acc[i][j] = (floatx4){0.f, 0.f, 0.f, 0.f};

    uint4 Bcur[4], Bnext[4];
    #pragma unroll
    for (int j = 0; j < 4; ++j) Bnext[j] = (uint4){0u,0u,0u,0u};
    stageA(0, 0);
    loadB(0, Bcur);

    for (int kt = 0; kt < 27; ++kt) {
        int buf = kt & 1;
        __syncthreads();
        #pragma unroll
        for (int j = 0; j < 4; ++j) {
            int chunk = (oct>>2)*8 + (prj[j]>>4);
            *(uint4*)&Bs[chunk*512 + ((oct&3)*16 + ((prj[j]&15) ^ oct))*8] = Bcur[j];
        }
        __syncthreads();
        if (kt < 26) { stageA(kt+1, buf^1); loadB(kt+1, Bnext); }
        #pragma unroll
        for (int ks = 0; ks < 2; ++ks) {
            int swzB = (lq*16 + (lm ^ (ks*4 + lq)))*8;
            shortx8 a[4], b[4];
            #pragma unroll
            for (int i = 0; i < 4; ++i) a[i] = *(const shortx8*)&As[buf][(ks*8 + 4*mh + i)*512 + lane*8];
            #pragma unroll
            for (int j = 0; j < 4; ++j) b[j] = *(const shortx8*)&Bs[(ks*8 + 4*nh + j)*512 + swzB];
            #pragma unroll
            for (int i = 0; i < 4; ++i)
                #pragma unroll
                for (int j = 0; j < 4; ++j)
                    acc[i][j] = __builtin_amdgcn_mfma_f32_16x16x32_bf16(a[i], b[j], acc[i][j], 0, 0, 0);
        }
        #pragma unroll
        for (int j = 0; j < 4; ++j) Bcur[j] = Bnext[j];
    }

    #pragma unroll
    for (int i = 0; i < 4; ++i) {
        int cob = m0 + (4*mh+i)*16 + lq*4;
        #pragma unroll
        for (int r = 0; r < 4; ++r) {
            int co = cob + r;    // < 640 always (mt <= 4)
            float bv = bias[co];
            int row2 = co / 3, comp = co % 3;
            size_t base = (size_t)row2*P_*3 + comp;
            #pragma unroll
            for (int j = 0; j < 4; ++j) {
                int col = p0 + (4*nh+j)*16 + lm;
                out2[base + (size_t)col*3] = f2b(acc[i][j][r] + bv);
            }
        }
    }
}

// ---------------------------------------------------------------------------
// conv_off tail: rows 640..655 (648..655 zero-padded). 16x128 tile.
// ---------------------------------------------------------------------------
__global__ __launch_bounds__(256) void conv_off_tail(
    const unsigned short* __restrict__ A,    // A1k [768][1728]
    const unsigned short* __restrict__ xt,   // [N][P][64] bf16
    const float* __restrict__ bias,          // [648]
    unsigned short* __restrict__ off2)       // [N][216*P][3] bf16
{
    __shared__ __align__(16) short As[54*512];
    __shared__ __align__(16) short Bs[16*512];
    int tid = threadIdx.x;
    int w = tid >> 6, lane = tid & 63;
    int n  = blockIdx.x / 196;
    int p0 = (blockIdx.x % 196)*128;
    int lm = lane & 15, lq = lane >> 4;

    const unsigned short* xtn = xt + (size_t)n*P_*C_;
    unsigned short* out2 = off2 + (size_t)n*216*P_*3;

    const char* Abase = (const char*)A + (size_t)(640 + lm)*KB_ + lq*16;
    for (int ch = w; ch < 54; ch += 4)
        __builtin_amdgcn_global_load_lds((const AS1 unsigned*)(Abase + ch*64),
                                         (AS3 unsigned*)(As + ch*512), 16, 0, 0);

    int oct = lane & 7;
    int prj[4], dj[4], hj[4], wj[4];
    #pragma unroll
    for (int j = 0; j < 4; ++j) {
        int prow = j*32 + w*8 + (lane >> 3);
        prj[j] = prow;
        int p = p0 + prow;
        dj[j] = p / HW_;
        int hw2 = p % HW_;
        hj[j] = hw2 / W_;
        wj[j] = hw2 % W_;
    }
    auto loadB = [&](int kt, uint4* B) {
        int kd = kt/9 - 1, kh = (kt/3)%3 - 1, kw = kt%3 - 1;
        int delta = kd*HW_ + kh*W_ + kw;
        #pragma unroll
        for (int j = 0; j < 4; ++j) {
            bool v = ((unsigned)(dj[j]+kd) < (unsigned)D_) &&
                     ((unsigned)(hj[j]+kh) < (unsigned)H_) &&
                     ((unsigned)(wj[j]+kw) < (unsigned)W_);
            uint4 val = {0u,0u,0u,0u};
            if (v) val = *(const uint4*)(xtn + (size_t)(p0 + prj[j] + delta)*C_ + oct*8);
            B[j] = val;
        }
    };

    floatx4 acc[2];
    acc[0] = (floatx4){0.f,0.f,0.f,0.f};
    acc[1] = (floatx4){0.f,0.f,0.f,0.f};

    uint4 Bcur[4], Bnext[4];
    #pragma unroll
    for (int j = 0; j < 4; ++j) Bnext[j] = (uint4){0u,0u,0u,0u};
    loadB(0, Bcur);

    for (int kt = 0; kt < 27; ++kt) {
        __syncthreads();
        #pragma unroll
        for (int j = 0; j < 4; ++j) {
            int chunk = (oct>>2)*8 + (prj[j]>>4);
            *(uint4*)&Bs[chunk*512 + ((oct&3)*16 + ((prj[j]&15) ^ oct))*8] = Bcur[j];
        }
        __syncthreads();
        if (kt < 26) loadB(kt+1, Bnext);
        #pragma unroll
        for (int ks = 0; ks < 2; ++ks) {
            int swzB = (lq*16 + (lm ^ (ks*4 + lq)))*8;
            shortx8 a = *(const shortx8*)&As[(kt*2 + ks)*512 + lane*8];
            #pragma unroll
            for (int j = 0; j < 2; ++j) {
                shortx8 b = *(const shortx8*)&Bs[(ks*8 + w*2 + j)*512 + swzB];
                acc[j] = __builtin_amdgcn_mfma_f32_16x16x32_bf16(a, b, acc[j], 0, 0, 0);
            }
        }
        #pragma unroll
        for (int j = 0; j < 4; ++j) Bcur[j] = Bnext[j];
    }

    #pragma unroll
    for (int j = 0; j < 2; ++j) {
        #pragma unroll
        for (int r = 0; r < 4; ++r) {
            int co = 640 + lq*4 + r;
            if (co < CO_OFF_) {
                int col = p0 + w*32 + j*16 + lm;
                out2[((size_t)(co/3)*P_ + col)*3 + (co%3)] = f2b(acc[j][r] + bias[co]);
            }
        }
    }
}

// ---------------------------------------------------------------------------
// deform fused v5: N=32 tiles, A dbuf + B dbuf in LDS -> ONE barrier per kt.
// Factorized trilinear: per-axis clamp/mask, 4 row-bases, corner = add+mul.
// ---------------------------------------------------------------------------
__global__ __launch_bounds__(256) void deform_fused(
    const unsigned short* __restrict__ xt,   // [N][P][64] bf16
    const unsigned short* __restrict__ off2, // [N][216*P][3] bf16
    const unsigned short* __restrict__ A,    // A1t [64][1728]
    unsigned short* __restrict__ y1t)        // [N][P][64] bf16
{
    __shared__ __align__(16) short SH[12288]; // A dbuf 2x4096, B dbuf 2x2048
    int tid = threadIdx.x;
    int w = tid >> 6, lane = tid & 63;
    int n  = blockIdx.x / (P_/32);
    int p0 = (blockIdx.x % (P_/32))*32;
    int lm = lane & 15, lq = lane >> 4;

    const unsigned short* offn = off2 + (size_t)n*216*P_*3;
    const uint4* xg0 = (const uint4*)(xt + (size_t)n*P_*C_);

    const char* Ab = (const char*)A + (size_t)(w*16 + lm)*KB_ + lq*16;

    int g = lane & 7;
    int prow = tid >> 3;          // 0..31
    int p = p0 + prow;
    int dd = p / HW_;
    int hw2 = p % HW_;
    int hh = hw2 / W_;
    int ww = hw2 % W_;
    int bchunk = (g>>2)*2 + (prow>>4);
    int boffs  = ((g&3)*16 + ((prow&15) ^ g))*8;

    auto stageA = [&](int kt, int buf) {
        __builtin_amdgcn_global_load_lds((const AS1 unsigned*)(Ab + kt*128),      (AS3 unsigned*)(SH + buf*4096 + w*512),     16, 0, 0);
        __builtin_amdgcn_global_load_lds((const AS1 unsigned*)(Ab + kt*128 + 64), (AS3 unsigned*)(SH + buf*4096 + (4+w)*512), 16, 0, 0);
    };
    auto loadOff = [&](int kt, float* o) {
        size_t idx = ((size_t)(g*K_ + kt)*P_ + p)*3;
        o[0] = b2f(offn[idx]);
        o[1] = b2f(offn[idx + 1]);
        o[2] = b2f(offn[idx + 2]);
    };
    auto issueCorners = [&](int kt, float* o, uint4* V, float* Wt) {
        int kd = kt/9 - 1, kh = (kt/3)%3 - 1, kw = kt%3 - 1;
        float pd = (float)(dd + kd) + o[0];
        float ph = (float)(hh + kh) + o[1];
        float pw = (float)(ww + kw) + o[2];
        float fd0 = floorf(pd), fh0 = floorf(ph), fw0 = floorf(pw);
        int d0 = (int)fd0, h0 = (int)fh0, w0i = (int)fw0;
        float fd = pd - fd0, fh = ph - fh0, fw = pw - fw0;
        // per-axis clamped coords + mask-folded weights
        int dc0 = min(max(d0, 0), D_-1),   dc1 = min(max(d0+1, 0), D_-1);
        int hc0 = min(max(h0, 0), H_-1),   hc1 = min(max(h0+1, 0), H_-1);
        int wc0 = min(max(w0i, 0), W_-1),  wc1 = min(max(w0i+1, 0), W_-1);
        float wd0 = ((unsigned)d0      < (unsigned)D_) ? 1.f - fd : 0.f;
        float wd1 = ((unsigned)(d0+1)  < (unsigned)D_) ? fd       : 0.f;
        float wh0 = ((unsigned)h0      < (unsigned)H_) ? 1.f - fh : 0.f;
        float wh1 = ((unsigned)(h0+1)  < (unsigned)H_) ? fh       : 0.f;
        float ww0 = ((unsigned)w0i     < (unsigned)W_) ? 1.f - fw : 0.f;
        float ww1 = ((unsigned)(w0i+1) < (unsigned)W_) ? fw       : 0.f;
        int rb00 = (dc0*H_ + hc0)*W_, rb01 = (dc0*H_ + hc1)*W_;
        int rb10 = (dc1*H_ + hc0)*W_, rb11 = (dc1*H_ + hc1)*W_;
        float wdh00 = wd0*wh0, wdh01 = wd0*wh1, wdh10 = wd1*wh0, wdh11 = wd1*wh1;
        V[0] = xg0[(size_t)(rb00+wc0)*8 + g];  Wt[0] = wdh00*ww0;
        V[1] = xg0[(size_t)(rb00+wc1)*8 + g];  Wt[1] = wdh00*ww1;
        V[2] = xg0[(size_t)(rb01+wc0)*8 + g];  Wt[2] = wdh01*ww0;
        V[3] = xg0[(size_t)(rb01+wc1)*8 + g];  Wt[3] = wdh01*ww1;
        V[4] = xg0[(size_t)(rb10+wc0)*8 + g];  Wt[4] = wdh10*ww0;
        V[5] = xg0[(size_t)(rb10+wc1)*8 + g];  Wt[5] = wdh10*ww1;
        V[6] = xg0[(size_t)(rb11+wc0)*8 + g];  Wt[6] = wdh11*ww0;
        V[7] = xg0[(size_t)(rb11+wc1)*8 + g];  Wt[7] = wdh11*ww1;
    };
    auto reduceCorners = [&](uint4* V, float* Wt, uint4& o4) {
        float res[CPG_];
        #pragma unroll
        for (int c = 0; c < CPG_; ++c) res[c] = 0.f;
        #pragma unroll
        for (int c = 0; c < 8; ++c) {
            uint4 v4 = V[c];
            float wgt = Wt[c];
            res[0] = fmaf(wgt, lof(v4.x), res[0]);
            res[1] = fmaf(wgt, hif(v4.x), res[1]);
            res[2] = fmaf(wgt, lof(v4.y), res[2]);
            res[3] = fmaf(wgt, hif(v4.y), res[3]);
            res[4] = fmaf(wgt, lof(v4.z), res[4]);
            res[5] = fmaf(wgt, hif(v4.z), res[5]);
            res[6] = fmaf(wgt, lof(v4.w), res[6]);
            res[7] = fmaf(wgt, hif(v4.w), res[7]);
        }
        o4.x = (unsigned)f2b(res[0]) | ((unsigned)f2b(res[1]) << 16);
        o4.y = (unsigned)f2b(res[2]) | ((unsigned)f2b(res[3]) << 16);
        o4.z = (unsigned)f2b(res[4]) | ((unsigned)f2b(res[5]) << 16);
        o4.w = (unsigned)f2b(res[6]) | ((unsigned)f2b(res[7]) << 16);
    };

    int mh = w >> 1, nh = w & 1;
    floatx4 acc[2];
    acc[0] = (floatx4){0.f,0.f,0.f,0.f};
    acc[1] = (floatx4){0.f,0.f,0.f,0.f};

    float offA[3], offB[3], offT[3];
    uint4 Vv[8]; float Wt[8];
    uint4 o4cur;

    stageA(0, 0);
    loadOff(0, offA);
    loadOff(1, offB);
    issueCorners(0, offA, Vv, Wt);
    reduceCorners(Vv, Wt, o4cur);
    *(uint4*)&SH[8192 + bchunk*512 + boffs] = o4cur;   // B(0) -> Bs buf 0

    for (int kt = 0; kt < 27; ++kt) {
        int buf = kt & 1;
        __syncthreads();   // Bs[buf] writes + As[buf] staging drained
        if (kt < 26) {
            stageA(kt+1, buf^1);
            if (kt < 25) loadOff(kt+2, offT);
            issueCorners(kt+1, offB, Vv, Wt);
        }
        #pragma unroll
        for (int ks = 0; ks < 2; ++ks) {
            int swzB = (lq*16 + (lm ^ (ks*4 + lq)))*8;
            shortx8 b = *(const shortx8*)&SH[8192 + buf*2048 + (ks*2 + nh)*512 + swzB];
            #pragma unroll
            for (int i = 0; i < 2; ++i) {
                shortx8 a = *(const shortx8*)&SH[buf*4096 + (ks*4 + 2*mh+i)*512 + lane*8];
                acc[i] = __builtin_amdgcn_mfma_f32_16x16x32_bf16(a, b, acc[i], 0, 0, 0);
            }
        }
        if (kt < 26) {
            reduceCorners(Vv, Wt, o4cur);
            *(uint4*)&SH[8192 + (buf^1)*2048 + bchunk*512 + boffs] = o4cur;
            offB[0] = offT[0]; offB[1] = offT[1]; offB[2] = offT[2];
        }
    }

    // epilogue: transpose 64o x 32p tile to y1t[p][o] via LDS (stride 72)
    __syncthreads();
    #pragma unroll
    for (int i = 0; i < 2; ++i) {
        int ob = mh*32 + i*16 + lq*4;
        int pc = nh*16 + lm;
        #pragma unroll
        for (int rr = 0; rr < 4; ++rr)
            SH[pc*72 + ob + rr] = (short)f2b(acc[i][rr]);
    }
    __syncthreads();
    {
        int row = tid >> 3, seg = tid & 7;
        uint4 v = *(const uint4*)&SH[row*72 + seg*8];
        *(uint4*)(y1t + ((size_t)n*P_ + p0 + row)*C_ + seg*8) = v;
    }
}

// ---------------------------------------------------------------------------
// conv2 fused (R12 register-B version, unchanged)
// ---------------------------------------------------------------------------
__global__ __launch_bounds__(256) void conv2_fused(
    const unsigned short* __restrict__ y1t,  // [N][P][64] bf16
    const float* __restrict__ st1,           // [64] scale, [64] shift
    const unsigned short* __restrict__ A,    // A2t [64][1728]
    const float* __restrict__ bias,          // [64]
    unsigned short* __restrict__ y2)         // [N][64][P] bf16
{
    __shared__ __align__(16) short As[2][4096];
    __shared__ float sc[64], sf[64];
    int tid = threadIdx.x;
    if (tid < 64) sc[tid] = st1[tid];
    else if (tid < 128) sf[tid-64] = st1[tid];
    int w = tid >> 6, lane = tid & 63;
    int n  = blockIdx.x / (P_/64);
    int p0 = (blockIdx.x % (P_/64))*64;
    int lm = lane & 15, lq = lane >> 4;

    const unsigned short* y1n = y1t + (size_t)n*P_*C_;
    unsigned short* y2n = y2 + (size_t)n*C_*P_;
    const char* Ab = (const char*)A + (size_t)(w*16 + lm)*KB_ + lq*16;

    int p = p0 + w*16 + lm;
    int dd = p / HW_, hw2 = p % HW_;
    int hh = hw2 / W_, ww = hw2 % W_;

    auto stageA = [&](int kt, int buf) {
        __builtin_amdgcn_global_load_lds((const AS1 unsigned*)(Ab + kt*128),      (AS3 unsigned*)(&As[buf][w*512]),     16, 0, 0);
        __builtin_amdgcn_global_load_lds((const AS1 unsigned*)(Ab + kt*128 + 64), (AS3 unsigned*)(&As[buf][(4+w)*512]), 16, 0, 0);
    };
    auto issueV = [&](int kt, uint4* V, int& M) {
        int kd = kt/9 - 1, kh = (kt/3)%3 - 1, kw = kt%3 - 1;
        int delta = kd*HW_ + kh*W_ + kw;
        bool v = ((unsigned)(dd+kd) < (unsigned)D_) &&
                 ((unsigned)(hh+kh) < (unsigned)H_) &&
                 ((unsigned)(ww+kw) < (unsigned)W_);
        M = v ? 1 : 0;
        #pragma unroll
        for (int ks = 0; ks < 2; ++ks) {
            uint4 val = {0u,0u,0u,0u};
            if (v) val = *(const uint4*)(y1n + (size_t)(p + delta)*C_ + (ks*4 + lq)*8);
            V[ks] = val;
        }
    };
    auto reduceT = [&](uint4 V, int ks, int M) -> shortx8 {
        uint4 o4 = {0u,0u,0u,0u};
        if (M) {
            int cb = (ks*4 + lq)*8;
            float r0 = fmaxf(lof(V.x)*sc[cb+0] + sf[cb+0], 0.f);
            float r1 = fmaxf(hif(V.x)*sc[cb+1] + sf[cb+1], 0.f);
            float r2 = fmaxf(lof(V.y)*sc[cb+2] + sf[cb+2], 0.f);
            float r3 = fmaxf(hif(V.y)*sc[cb+3] + sf[cb+3], 0.f);
            float r4 = fmaxf(lof(V.z)*sc[cb+4] + sf[cb+4], 0.f);
            float r5 = fmaxf(hif(V.z)*sc[cb+5] + sf[cb+5], 0.f);
            float r6 = fmaxf(lof(V.w)*sc[cb+6] + sf[cb+6], 0.f);
            float r7 = fmaxf(hif(V.w)*sc[cb+7] + sf[cb+7], 0.f);
            o4.x = (unsigned)f2b(r0) | ((unsigned)f2b(r1) << 16);
            o4.y = (unsigned)f2b(r2) | ((unsigned)f2b(r3) << 16);
            o4.z = (unsigned)f2b(r4) | ((unsigned)f2b(r5) << 16);
            o4.w = (unsigned)f2b(r6) | ((unsigned)f2b(r7) << 16);
        }
        return *(shortx8*)&o4;
    };

    floatx4 acc[4];
    #pragma unroll
    for (int i = 0; i < 4; ++i) acc[i] = (floatx4){0.f,0.f,0.f,0.f};

    uint4 V[2];
    int M;
    stageA(0, 0);
    issueV(0, V, M);

    for (int kt = 0; kt < 27; ++kt) {
        int buf = kt & 1;
        __syncthreads();
        if (kt < 26) stageA(kt+1, buf^1);
        shortx8 b0 = reduceT(V[0], 0, M);
        shortx8 b1 = reduceT(V[1], 1, M);
        if (kt < 26) issueV(kt+1, V, M);
        #pragma unroll
        for (int i = 0; i < 4; ++i) {
            shortx8 a = *(const shortx8*)&As[buf][(0*4 + i)*512 + lane*8];
            acc[i] = __builtin_amdgcn_mfma_f32_16x16x32_bf16(a, b0, acc[i], 0, 0, 0);
        }
        #pragma unroll
        for (int i = 0; i < 4; ++i) {
            shortx8 a = *(const shortx8*)&As[buf][(1*4 + i)*512 + lane*8];
            acc[i] = __builtin_amdgcn_mfma_f32_16x16x32_bf16(a, b1, acc[i], 0, 0, 0);
        }
    }

    #pragma unroll
    for (int i = 0; i < 4; ++i) {
        #pragma unroll
        for (int r = 0; r < 4; ++r) {
            int co = i*16 + lq*4 + r;
            y2n[(size_t)co*P_ + p] = f2b(acc[i][r] + bias[co]);
        }
    }
}

// ---------------------------------------------------------------------------
// BN1 stats from y1t [N*P][64]: partial sums per 512-row block, then finalize
// ---------------------------------------------------------------------------
__global__ __launch_bounds__(256) void stats_partial_kernel(
    const unsigned short* __restrict__ y1t, float* __restrict__ part)
{
    int b = blockIdx.x, tid = threadIdx.x;
    int c = tid & 63, sub = tid >> 6;
    float s = 0.f, q = 0.f;
    for (int rr = 0; rr < 128; ++rr) {
        int row = b*512 + sub*128 + rr;
        float v = b2f(y1t[(size_t)row*C_ + c]);
        s += v;
        q = fmaf(v, v, q);
    }
    __shared__ float ss[256], qq[256];
    ss[tid] = s; qq[tid] = q;
    __syncthreads();
    if (tid < 64) {
        float S = ss[tid] + ss[64+tid] + ss[128+tid] + ss[192+tid];
        float Q = qq[tid] + qq[64+tid] + qq[128+tid] + qq[192+tid];
        part[b*128 + tid]      = S;
        part[b*128 + 64 + tid] = Q;
    }
}

__global__ void stats_final_kernel(
    const float* __restrict__ part,
    const float* __restrict__ gamma, const float* __restrict__ beta,
    float* __restrict__ st1)
{
    int c = threadIdx.x;  // 64 threads
    float S = 0.f, Q = 0.f;
    for (int b = 0; b < 98; ++b) {
        S += part[b*128 + c];
        Q += part[b*128 + 64 + c];
    }
    const float inv = 1.f / (float)(N_*P_);
    float m = S * inv;
    float var = Q * inv - m*m;
    float scale = rsqrtf(var + 1e-5f) * gamma[c];
    st1[c]      = scale;
    st1[64 + c] = beta[c] - m*scale;
}

// ---------------------------------------------------------------------------
__global__ __launch_bounds__(256) void bn_stats_kernel(
    const unsigned short* __restrict__ src, float* __restrict__ stats)
{
    int c   = blockIdx.x;
    int tid = threadIdx.x;
    float s = 0.f, q = 0.f;
    for (int n = 0; n < N_; ++n) {
        const unsigned short* p = src + ((size_t)n*C_ + c)*P_;
        for (int i = tid; i < P_; i += 256) {
            float v = b2f(p[i]);
            s += v;
            q = fmaf(v, v, q);
        }
    }
    #pragma unroll
    for (int o = 32; o; o >>= 1) {
        s += __shfl_down(s, o);
        q += __shfl_down(q, o);
    }
    __shared__ float sh[2][4];
    int wave = tid >> 6;
    if ((tid & 63) == 0) { sh[0][wave] = s; sh[1][wave] = q; }
    __syncthreads();
    if (tid == 0) {
        float S = sh[0][0] + sh[0][1] + sh[0][2] + sh[0][3];
        float Q = sh[1][0] + sh[1][1] + sh[1][2] + sh[1][3];
        const float inv = 1.f / (float)(N_*P_);
        float m  = S * inv;
        float var = Q * inv - m*m;
        stats[c]      = m;
        stats[C_ + c] = rsqrtf(var + 1e-5f);
    }
}

__global__ __launch_bounds__(256) void bn_add_relu_kernel(
    const unsigned short* __restrict__ y2, const float* __restrict__ x,
    const float* __restrict__ stats,
    const float* __restrict__ gamma, const float* __restrict__ beta,
    float* __restrict__ out)
{
    size_t idx = (size_t)blockIdx.x*256 + threadIdx.x;
    int c = (int)((idx / P_) % C_);
    float v = (b2f(y2[idx]) - stats[c]) * stats[C_ + c] * gamma[c] + beta[c] + x[idx];
    out[idx] = fmaxf(v, 0.f);
}

// ---------------------------------------------------------------------------
extern "C" void kernel_launch(void* const* d_in, const int* in_sizes, int n_in,
                              void* d_out, int out_size, void* d_ws, size_t ws_size,
                              hipStream_t stream) {
    const float* x     = (const float*)d_in[0];
    const float* w_off = (const float*)d_in[1];
    const float* b_off = (const float*)d_in[2];
    const float* w1    = (const float*)d_in[3];
    const float* g1    = (const float*)d_in[4];
    const float* be1   = (const float*)d_in[5];
    const float* w2    = (const float*)d_in[6];
    const float* b2    = (const float*)d_in[7];
    const float* g2    = (const float*)d_in[8];
    const float* be2   = (const float*)d_in[9];
    float* out = (float*)d_out;

    // workspace (~88 MB)
    float* st1  = (float*)d_ws;                              // 128 (scale/shift)
    float* st2  = st1 + 128;                                 // 128 (mean/rstd)
    float* part = st2 + 128;                                 // 98*128
    unsigned short* off2 = (unsigned short*)(part + 98*128); // N*216*P*3 bf16 (65 MB)
    unsigned short* xt  = off2 + (size_t)N_*216*P_*3;        // N*P*64 bf16 (6.4 MB)
    unsigned short* y1t = xt  + (size_t)N_*P_*C_;            // N*P*64 bf16 (6.4 MB)
    unsigned short* y2  = y1t + (size_t)N_*P_*C_;            // N*64*P bf16 (6.4 MB)
    unsigned short* A1k = y2  + (size_t)N_*C_*P_;            // 768*1728 bf16 (2.65 MB)
    unsigned short* A1t = A1k + (size_t)MP_*KK_;             // 64*1728 bf16
    unsigned short* A2t = A1t + (size_t)C_*KK_;              // 64*1728 bf16

    // prep
    transpose_xt_kernel<<<N_*(P_/64), 256, 0, stream>>>(x, xt);
    permA1k_kernel<<<(MP_*KK_+255)/256, 256, 0, stream>>>(w_off, A1k);
    perm_w_kernel<<<(C_*KK_+255)/256, 256, 0, stream>>>(w1, A1t);
    perm_w_kernel<<<(C_*KK_+255)/256, 256, 0, stream>>>(w2, A2t);

    // conv_off fused -> off2 (both n): main (rows 0..639) + tail (640..647)
    conv_off_fused<<<2*980, 256, 0, stream>>>(A1k, xt, b_off, off2);
    conv_off_tail<<<2*196, 256, 0, stream>>>(A1k, xt, b_off, off2);

    // deform fused -> y1t (both n), single-barrier dbuf pipeline
    deform_fused<<<N_*(P_/32), 256, 0, stream>>>(xt, off2, A1t, y1t);

    // BN1 scale/shift
    stats_partial_kernel<<<98, 256, 0, stream>>>(y1t, part);
    stats_final_kernel<<<1, 64, 0, stream>>>(part, g1, be1, st1);

    // conv2 fused (BN1+ReLU on read) -> y2 (both n), register-B
    conv2_fused<<<N_*(P_/64), 256, 0, stream>>>(y1t, st1, A2t, b2, y2);

    // BN2 + residual + ReLU -> out (fp32)
    bn_stats_kernel<<<C_, 256, 0, stream>>>(y2, st2);
    bn_add_relu_kernel<<<(N_*C_*P_)/256, 256, 0, stream>>>(y2, x, st2, g2, be2, out);
}